// Round 7
// baseline (1368.949 us; speedup 1.0000x reference)
//
#include <hip/hip_runtime.h>

#define NSEQ 2048
#define BATCH 16
#define HDIM 256
#define PDIM 256
#define NLAYER 4
#define NCHUNK 64
#define CHLEN (NSEQ / NCHUNK)   // 32

typedef __attribute__((ext_vector_type(8))) short short8;
typedef __attribute__((ext_vector_type(4))) float f32x4;
typedef unsigned int u32;
typedef unsigned short u16;

__device__ __forceinline__ float gelu_tanh(float x) {
    float z = 0.7978845608028654f * (x + 0.044715f * x * x * x);
    return 0.5f * x * (1.f + tanhf(z));
}

__device__ __forceinline__ unsigned cvt_pk_bf16(float a, float b) {
    unsigned r;
    asm("v_cvt_pk_bf16_f32 %0, %1, %2" : "=v"(r) : "v"(a), "v"(b));
    return r;
}
__device__ __forceinline__ float bflo(unsigned u) { return __uint_as_float(u << 16); }
__device__ __forceinline__ float bfhi(unsigned u) { return __uint_as_float(u & 0xffff0000u); }

__device__ __forceinline__ void split4(const float4 v, uint2& h, uint2& l) {
    h.x = cvt_pk_bf16(v.x, v.y);
    h.y = cvt_pk_bf16(v.z, v.w);
    l.x = cvt_pk_bf16(v.x - bflo(h.x), v.y - bfhi(h.x));
    l.y = cvt_pk_bf16(v.z - bflo(h.y), v.w - bfhi(h.y));
}
__device__ __forceinline__ void split1(float v, u16& h, u16& lo) {
    const unsigned hp = cvt_pk_bf16(v, v);
    h = (u16)hp;
    const float res = v - __uint_as_float((hp & 0xffffu) << 16);
    lo = (u16)cvt_pk_bf16(res, res);
}

typedef __attribute__((address_space(1))) const u32 gu32;
typedef __attribute__((address_space(3))) u32 lu32;
__device__ __forceinline__ void gl16(const void* g, void* l) {
    __builtin_amdgcn_global_load_lds((gu32*)g, (lu32*)l, 16, 0, 0);
}

// ---------------- Mr = B_re@C_re - B_im@C_im (per layer), fp32 vector GEMM ----------------
__global__ __launch_bounds__(256) void mr_gemm(const float* __restrict__ Bre_g,
                                               const float* __restrict__ Bim_g,
                                               const float* __restrict__ Cre_g,
                                               const float* __restrict__ Cim_g,
                                               float* __restrict__ MrF) {
    const size_t lofs = (size_t)blockIdx.z * 65536;
    const float* Ar = Bre_g + lofs;
    const float* Ai = Bim_g + lofs;
    const float* Wr = Cre_g + lofs;
    const float* Wi = Cim_g + lofs;
    float* out = MrF + lofs;
    __shared__ float Asr[32][68], Asi[32][68], Wsr[32][68], Wsi[32][68];
    const int m0 = blockIdx.x << 6, n0 = blockIdx.y << 6;
    const int tx = threadIdx.x & 15, ty = threadIdx.x >> 4;
    const int ar = threadIdx.x >> 3, ak = (threadIdx.x & 7) << 2;
    const int wk = threadIdx.x >> 4, wn = (threadIdx.x & 15) << 2;
    float acc[4][4] = {};
    for (int k0 = 0; k0 < 256; k0 += 32) {
#pragma unroll
        for (int it = 0; it < 2; ++it) {
            const int r = (it << 5) + ar;
            float4 v = *(const float4*)&Ar[(size_t)(m0 + r) * 256 + k0 + ak];
            Asr[ak + 0][r] = v.x; Asr[ak + 1][r] = v.y; Asr[ak + 2][r] = v.z; Asr[ak + 3][r] = v.w;
            v = *(const float4*)&Ai[(size_t)(m0 + r) * 256 + k0 + ak];
            Asi[ak + 0][r] = v.x; Asi[ak + 1][r] = v.y; Asi[ak + 2][r] = v.z; Asi[ak + 3][r] = v.w;
        }
#pragma unroll
        for (int it = 0; it < 2; ++it) {
            const int k = (it << 4) + wk;
            *(float4*)&Wsr[k][wn] = *(const float4*)&Wr[(size_t)(k0 + k) * 256 + n0 + wn];
            *(float4*)&Wsi[k][wn] = *(const float4*)&Wi[(size_t)(k0 + k) * 256 + n0 + wn];
        }
        __syncthreads();
#pragma unroll 8
        for (int k = 0; k < 32; ++k) {
            const float4 a_r = *(const float4*)&Asr[k][ty << 2];
            const float4 a_i = *(const float4*)&Asi[k][ty << 2];
            const float4 w_r = *(const float4*)&Wsr[k][tx << 2];
            const float4 w_i = *(const float4*)&Wsi[k][tx << 2];
            const float aar[4] = {a_r.x, a_r.y, a_r.z, a_r.w};
            const float aai[4] = {a_i.x, a_i.y, a_i.z, a_i.w};
            const float wwr[4] = {w_r.x, w_r.y, w_r.z, w_r.w};
            const float wwi[4] = {w_i.x, w_i.y, w_i.z, w_i.w};
#pragma unroll
            for (int i = 0; i < 4; ++i)
#pragma unroll
                for (int j = 0; j < 4; ++j)
                    acc[i][j] += aar[i] * wwr[j] - aai[i] * wwi[j];
        }
        __syncthreads();
    }
#pragma unroll
    for (int i = 0; i < 4; ++i) {
        float4 o = {acc[i][0], acc[i][1], acc[i][2], acc[i][3]};
        *(float4*)&out[(size_t)(m0 + (ty << 2) + i) * 256 + n0 + (tx << 2)] = o;
    }
}

// ---------------- weight prep: fp32 (K,256) -> split bf16 [k/8][ldn][8] ----------------
struct PrepJob { const float* src; short* dhi; short* dlo; int ldn; int colofs; float sgn; };
struct PrepArgs { PrepJob j[28]; };

__global__ void prep_w(PrepArgs a) {
    const PrepJob jb = a.j[blockIdx.y];
    __shared__ float t[8][256];
    const int kg = blockIdx.x, tid = threadIdx.x;
    const int r = tid >> 5, c = (tid & 31) * 8;
    const float* src = jb.src + (size_t)(kg * 8 + r) * 256 + c;
    *(float4*)&t[r][c]     = *(const float4*)src;
    *(float4*)&t[r][c + 4] = *(const float4*)(src + 4);
    __syncthreads();
    const int n = tid;
    float x[8];
#pragma unroll
    for (int q = 0; q < 8; ++q) x[q] = t[q][n] * jb.sgn;
    uint4 h, l;
    h.x = cvt_pk_bf16(x[0], x[1]); h.y = cvt_pk_bf16(x[2], x[3]);
    h.z = cvt_pk_bf16(x[4], x[5]); h.w = cvt_pk_bf16(x[6], x[7]);
    l.x = cvt_pk_bf16(x[0] - bflo(h.x), x[1] - bfhi(h.x));
    l.y = cvt_pk_bf16(x[2] - bflo(h.y), x[3] - bfhi(h.y));
    l.z = cvt_pk_bf16(x[4] - bflo(h.z), x[5] - bfhi(h.z));
    l.w = cvt_pk_bf16(x[6] - bflo(h.w), x[7] - bfhi(h.w));
    const size_t o = ((size_t)kg * jb.ldn + jb.colofs + n) * 8;
    *(uint4*)&jb.dhi[o] = h;
    *(uint4*)&jb.dlo[o] = l;
}

// ---------------- LayerNorm: one wave per token, pre-split bf16 output ----------------
__global__ void ln_wave(const float* __restrict__ u, const float* __restrict__ sc,
                        const float* __restrict__ bs,
                        short* __restrict__ outH, short* __restrict__ outL) {
    const int lane = threadIdx.x & 63;
    const int w = threadIdx.x >> 6;
    const size_t tok = (size_t)blockIdx.x * 4 + w;
    const size_t base = tok * 256 + (size_t)lane * 4;
    const float4 x = *(const float4*)&u[base];
    float s = x.x + x.y + x.z + x.w;
#pragma unroll
    for (int off = 32; off; off >>= 1) s += __shfl_xor(s, off, 64);
    const float mean = s * (1.f / 256.f);
    const float dx = x.x - mean, dy = x.y - mean, dz = x.z - mean, dw = x.w - mean;
    float v = dx * dx + dy * dy + dz * dz + dw * dw;
#pragma unroll
    for (int off = 32; off; off >>= 1) v += __shfl_xor(v, off, 64);
    const float rstd = rsqrtf(v * (1.f / 256.f) + 1e-5f);
    const float4 s4 = *(const float4*)&sc[lane * 4];
    const float4 b4 = *(const float4*)&bs[lane * 4];
    float4 o;
    o.x = dx * rstd * s4.x + b4.x;
    o.y = dy * rstd * s4.y + b4.y;
    o.z = dz * rstd * s4.z + b4.z;
    o.w = dw * rstd * s4.w + b4.w;
    uint2 h, lo;
    split4(o, h, lo);
    *(uint2*)&outH[base] = h;
    *(uint2*)&outL[base] = lo;
}

// ---------------- Bu+ymr GEMM: A(v_r) 128x32 reg-staged, W gl16, N up to 768 ----------------
// cols 0..511 -> BuB (ld 512); cols 512..767 -> ymr (ld 256)
__global__ __launch_bounds__(512, 4) void gemm_bu(
    const short* __restrict__ AH, const short* __restrict__ AL,
    const short* __restrict__ Whi_g, const short* __restrict__ Wlo_g,
    float* __restrict__ outBu, float* __restrict__ outY) {
    __shared__ short AsH[2][128 * 32], AsL[2][128 * 32];
    __shared__ short Wh[2][4 * 128 * 8], Wl[2][4 * 128 * 8];
    const int tid = threadIdx.x;
    const int m0 = blockIdx.x << 7, n0 = blockIdx.y << 7;
    const int wid = tid >> 6, l = tid & 63;
    const int wm = wid >> 2, wn = wid & 3;
    const int kq = l >> 4, lr = l & 15;
    const int sm = tid >> 2, sc = tid & 3;
    const int wslot = sc ^ ((sm >> 1) & 3);
    const int kgW = (tid >> 7) & 3, colw = tid & 127;

    f32x4 acc[4][2];
#pragma unroll
    for (int i = 0; i < 4; ++i)
#pragma unroll
        for (int j = 0; j < 2; ++j) acc[i][j] = {0.f, 0.f, 0.f, 0.f};

    auto stageW = [&](int k0, int buf) {
        const size_t so = ((size_t)((k0 >> 3) + kgW) * 768 + n0 + colw) * 8;
        gl16(Whi_g + so, &Wh[buf][(kgW * 128 + colw) * 8]);
        gl16(Wlo_g + so, &Wl[buf][(kgW * 128 + colw) * 8]);
    };
    auto loadA = [&](int k0, uint4& h, uint4& lo) {
        const size_t ab = (size_t)(m0 + sm) * 256 + k0 + sc * 8;
        h  = *(const uint4*)&AH[ab];
        lo = *(const uint4*)&AL[ab];
    };
    auto writeA = [&](int buf, const uint4 h, const uint4 lo) {
        const int cell = (sm * 4 + wslot) * 8;
        *(uint4*)&AsH[buf][cell] = h;
        *(uint4*)&AsL[buf][cell] = lo;
    };

    {
        uint4 p0, p1;
        loadA(0, p0, p1);
        stageW(0, 0);
        writeA(0, p0, p1);
    }
    const int sw = (lr >> 1) & 3;
    for (int t = 0; t < 8; ++t) {
        const int cur = t & 1, nxt = cur ^ 1;
        __syncthreads();
        const bool pre = (t + 1 < 8);
        uint4 nh, nl;
        if (pre) {
            loadA((t + 1) * 32, nh, nl);
            stageW((t + 1) * 32, nxt);
        }
        short8 ah[4], am[4];
#pragma unroll
        for (int i = 0; i < 4; ++i) {
            const int r = wm * 64 + i * 16 + lr;
            const int cell = (r * 4 + (kq ^ sw)) * 8;
            ah[i] = *(const short8*)&AsH[cur][cell];
            am[i] = *(const short8*)&AsL[cur][cell];
        }
#pragma unroll
        for (int j = 0; j < 2; ++j) {
            const int col = wn * 32 + j * 16 + lr;
            const short8 wh = *(const short8*)&Wh[cur][(kq * 128 + col) * 8];
            const short8 wl = *(const short8*)&Wl[cur][(kq * 128 + col) * 8];
#pragma unroll
            for (int i = 0; i < 4; ++i) {
                acc[i][j] = __builtin_amdgcn_mfma_f32_16x16x32_bf16(ah[i], wh, acc[i][j], 0, 0, 0);
                acc[i][j] = __builtin_amdgcn_mfma_f32_16x16x32_bf16(ah[i], wl, acc[i][j], 0, 0, 0);
                acc[i][j] = __builtin_amdgcn_mfma_f32_16x16x32_bf16(am[i], wh, acc[i][j], 0, 0, 0);
            }
        }
        if (pre) writeA(nxt, nh, nl);
    }
    const bool isY = (blockIdx.y >= 4);
#pragma unroll
    for (int j = 0; j < 2; ++j) {
        const int col = n0 + wn * 32 + j * 16 + lr;
#pragma unroll
        for (int i = 0; i < 4; ++i) {
#pragma unroll
            for (int r = 0; r < 4; ++r) {
                const int row = m0 + wm * 64 + i * 16 + kq * 4 + r;
                const float o = acc[i][j][r];
                if (isY) outY[(size_t)row * 256 + (col - 512)] = o;
                else     outBu[(size_t)row * 512 + col] = o;
            }
        }
    }
}

// ---------------- C GEMM (K=512, A=Xl): emits g_l and (optional) g_r ----------------
template <int WANT_R>
__global__ __launch_bounds__(512, 4) void gemm_c(
    const short* __restrict__ AH, const short* __restrict__ AL,
    const short* __restrict__ Whi_g, const short* __restrict__ Wlo_g,
    const float* __restrict__ ymr,
    short* __restrict__ glH, short* __restrict__ glL,
    short* __restrict__ grH, short* __restrict__ grL) {
    __shared__ short AsH[2][128 * 32], AsL[2][128 * 32];
    __shared__ short Wh[2][4 * 128 * 8], Wl[2][4 * 128 * 8];
    const int tid = threadIdx.x;
    const int m0 = blockIdx.x << 7, n0 = blockIdx.y << 7;
    const int wid = tid >> 6, l = tid & 63;
    const int wm = wid >> 2, wn = wid & 3;
    const int kq = l >> 4, lr = l & 15;
    const int sm = tid >> 2, sc = tid & 3;
    const int wslot = sc ^ ((sm >> 1) & 3);
    const int kgW = (tid >> 7) & 3, colw = tid & 127;

    f32x4 acc[4][2];
#pragma unroll
    for (int i = 0; i < 4; ++i)
#pragma unroll
        for (int j = 0; j < 2; ++j) acc[i][j] = {0.f, 0.f, 0.f, 0.f};

    auto stageW = [&](int k0, int buf) {
        const size_t so = ((size_t)((k0 >> 3) + kgW) * 256 + n0 + colw) * 8;
        gl16(Whi_g + so, &Wh[buf][(kgW * 128 + colw) * 8]);
        gl16(Wlo_g + so, &Wl[buf][(kgW * 128 + colw) * 8]);
    };
    auto loadA = [&](int k0, uint4& h, uint4& lo) {
        const size_t ab = (size_t)(m0 + sm) * 512 + k0 + sc * 8;
        h  = *(const uint4*)&AH[ab];
        lo = *(const uint4*)&AL[ab];
    };
    auto writeA = [&](int buf, const uint4 h, const uint4 lo) {
        const int cell = (sm * 4 + wslot) * 8;
        *(uint4*)&AsH[buf][cell] = h;
        *(uint4*)&AsL[buf][cell] = lo;
    };

    {
        uint4 p0, p1;
        loadA(0, p0, p1);
        stageW(0, 0);
        writeA(0, p0, p1);
    }
    const int sw = (lr >> 1) & 3;
    for (int t = 0; t < 16; ++t) {
        const int cur = t & 1, nxt = cur ^ 1;
        __syncthreads();
        const bool pre = (t + 1 < 16);
        uint4 nh, nl;
        if (pre) {
            loadA((t + 1) * 32, nh, nl);
            stageW((t + 1) * 32, nxt);
        }
        short8 ah[4], am[4];
#pragma unroll
        for (int i = 0; i < 4; ++i) {
            const int r = wm * 64 + i * 16 + lr;
            const int cell = (r * 4 + (kq ^ sw)) * 8;
            ah[i] = *(const short8*)&AsH[cur][cell];
            am[i] = *(const short8*)&AsL[cur][cell];
        }
#pragma unroll
        for (int j = 0; j < 2; ++j) {
            const int col = wn * 32 + j * 16 + lr;
            const short8 wh = *(const short8*)&Wh[cur][(kq * 128 + col) * 8];
            const short8 wl = *(const short8*)&Wl[cur][(kq * 128 + col) * 8];
#pragma unroll
            for (int i = 0; i < 4; ++i) {
                acc[i][j] = __builtin_amdgcn_mfma_f32_16x16x32_bf16(ah[i], wh, acc[i][j], 0, 0, 0);
                acc[i][j] = __builtin_amdgcn_mfma_f32_16x16x32_bf16(ah[i], wl, acc[i][j], 0, 0, 0);
                acc[i][j] = __builtin_amdgcn_mfma_f32_16x16x32_bf16(am[i], wh, acc[i][j], 0, 0, 0);
            }
        }
        if (pre) writeA(nxt, nh, nl);
    }
#pragma unroll
    for (int j = 0; j < 2; ++j) {
        const int col = n0 + wn * 32 + j * 16 + lr;
#pragma unroll
        for (int i = 0; i < 4; ++i) {
#pragma unroll
            for (int r = 0; r < 4; ++r) {
                const int row = m0 + wm * 64 + i * 16 + kq * 4 + r;
                const size_t o = (size_t)row * 256 + col;
                const float y = acc[i][j][r];
                u16 h, lo;
                split1(gelu_tanh(y), h, lo);
                glH[o] = (short)h; glL[o] = (short)lo;
                if constexpr (WANT_R) {
                    const float yr = y + ymr[o];
                    split1(gelu_tanh(yr), h, lo);
                    grH[o] = (short)h; grL[o] = (short)lo;
                }
            }
        }
    }
}

// ---------------- fused GLU GEMM, z-selected stream: u += (g@W1+b1)*sigmoid(g@W2+b2) ------
__global__ __launch_bounds__(512, 4) void glu_dma(
    const short* __restrict__ A0H, const short* __restrict__ A0L, float* __restrict__ u0,
    const short* __restrict__ A1H, const short* __restrict__ A1L, float* __restrict__ u1,
    const short* __restrict__ W1h, const short* __restrict__ W1l,
    const short* __restrict__ W2h, const short* __restrict__ W2l,
    const float* __restrict__ b1, const float* __restrict__ b2, int zero0) {
    __shared__ short AsH[2][128 * 32], AsL[2][128 * 32];
    __shared__ short Ws[2][4][4 * 64 * 8];
    const int z = blockIdx.z;
    const short* AH = z ? A1H : A0H;
    const short* AL = z ? A1L : A0L;
    float* u = z ? u1 : u0;
    const int tid = threadIdx.x;
    const int m0 = blockIdx.x << 7, n0 = blockIdx.y << 6;
    const int wid = tid >> 6, l = tid & 63;
    const int wm = wid >> 2, wn = wid & 3;
    const int kq = l >> 4, lr = l & 15;
    const int sm = tid >> 2, sc = tid & 3;
    const int wslot = sc ^ ((sm >> 1) & 3);
    const int kgW = (tid >> 6) & 3, colw = tid & 63, selLo = (tid >> 8) & 1;

    f32x4 acc1[4], acc2[4];
#pragma unroll
    for (int i = 0; i < 4; ++i) {
        acc1[i] = {0.f, 0.f, 0.f, 0.f};
        acc2[i] = {0.f, 0.f, 0.f, 0.f};
    }

    auto stageW = [&](int k0, int buf) {
        const size_t so = ((size_t)((k0 >> 3) + kgW) * 256 + n0 + colw) * 8;
        const short* s1 = selLo ? W1l : W1h;
        const short* s2 = selLo ? W2l : W2h;
        gl16(s1 + so, &Ws[buf][selLo][(kgW * 64 + colw) * 8]);
        gl16(s2 + so, &Ws[buf][2 + selLo][(kgW * 64 + colw) * 8]);
    };
    auto loadA = [&](int k0, uint4& h, uint4& lo) {
        const size_t ab = (size_t)(m0 + sm) * 256 + k0 + sc * 8;
        h  = *(const uint4*)&AH[ab];
        lo = *(const uint4*)&AL[ab];
    };
    auto writeA = [&](int buf, const uint4 h, const uint4 lo) {
        const int cell = (sm * 4 + wslot) * 8;
        *(uint4*)&AsH[buf][cell] = h;
        *(uint4*)&AsL[buf][cell] = lo;
    };

    {
        uint4 p0, p1;
        loadA(0, p0, p1);
        stageW(0, 0);
        writeA(0, p0, p1);
    }
    const int sw = (lr >> 1) & 3;
    for (int t = 0; t < 8; ++t) {
        const int cur = t & 1, nxt = cur ^ 1;
        __syncthreads();
        const bool pre = (t + 1 < 8);
        uint4 nh, nl;
        if (pre) {
            loadA((t + 1) * 32, nh, nl);
            stageW((t + 1) * 32, nxt);
        }
        short8 ah[4], am[4];
#pragma unroll
        for (int i = 0; i < 4; ++i) {
            const int r = wm * 64 + i * 16 + lr;
            const int cell = (r * 4 + (kq ^ sw)) * 8;
            ah[i] = *(const short8*)&AsH[cur][cell];
            am[i] = *(const short8*)&AsL[cur][cell];
        }
        {
            const int col = wn * 16 + lr;
            const short8 w1h = *(const short8*)&Ws[cur][0][(kq * 64 + col) * 8];
            const short8 w1l = *(const short8*)&Ws[cur][1][(kq * 64 + col) * 8];
            const short8 w2h = *(const short8*)&Ws[cur][2][(kq * 64 + col) * 8];
            const short8 w2l = *(const short8*)&Ws[cur][3][(kq * 64 + col) * 8];
#pragma unroll
            for (int i = 0; i < 4; ++i) {
                acc1[i] = __builtin_amdgcn_mfma_f32_16x16x32_bf16(ah[i], w1h, acc1[i], 0, 0, 0);
                acc1[i] = __builtin_amdgcn_mfma_f32_16x16x32_bf16(ah[i], w1l, acc1[i], 0, 0, 0);
                acc1[i] = __builtin_amdgcn_mfma_f32_16x16x32_bf16(am[i], w1h, acc1[i], 0, 0, 0);
                acc2[i] = __builtin_amdgcn_mfma_f32_16x16x32_bf16(ah[i], w2h, acc2[i], 0, 0, 0);
                acc2[i] = __builtin_amdgcn_mfma_f32_16x16x32_bf16(ah[i], w2l, acc2[i], 0, 0, 0);
                acc2[i] = __builtin_amdgcn_mfma_f32_16x16x32_bf16(am[i], w2h, acc2[i], 0, 0, 0);
            }
        }
        if (pre) writeA(nxt, nh, nl);
    }
    {
        const int col = n0 + wn * 16 + lr;
        const float c1 = b1[col], c2 = b2[col];
#pragma unroll
        for (int i = 0; i < 4; ++i) {
#pragma unroll
            for (int r = 0; r < 4; ++r) {
                const int row = m0 + wm * 64 + i * 16 + kq * 4 + r;
                const size_t o = (size_t)row * 256 + col;
                if (zero0 && ((row & (NSEQ - 1)) == 0)) {
                    u[o] = 0.f;
                } else {
                    const float t1 = acc1[i][r] + c1;
                    const float t2 = acc2[i][r] + c2;
                    u[o] += t1 * (1.f / (1.f + expf(-t2)));
                }
            }
        }
    }
}

// ---------------- embed GEMM: fp32 A (input), split in-kernel (runs once) ----------------
__global__ __launch_bounds__(512, 4) void gemm_embed(
    const float* __restrict__ A,
    const short* __restrict__ Whi_g, const short* __restrict__ Wlo_g,
    const float* __restrict__ bias,
    float* __restrict__ out0, float* __restrict__ out1) {
    __shared__ short As[2][2][4][128][8];
    __shared__ short Wsd[2][2][4][128][8];
    const int tid = threadIdx.x;
    const int m0 = blockIdx.x << 7, n0 = blockIdx.y << 7;
    const int wid = tid >> 6, l = tid & 63;
    const int wm = wid >> 2, wn = wid & 3;
    const int kq = l >> 4, lr = l & 15;
    const int sm = tid >> 2;
    const int klo = (tid & 3) * 4;
    const int kg0 = klo >> 3, sub0 = klo & 7;
    const int kgW = (tid >> 7) & 3, colw = tid & 127;

    f32x4 acc[4][2];
#pragma unroll
    for (int i = 0; i < 4; ++i)
#pragma unroll
        for (int j = 0; j < 2; ++j) acc[i][j] = {0.f, 0.f, 0.f, 0.f};

    auto stageW = [&](int k0, int buf) {
        const size_t so = ((size_t)((k0 >> 3) + kgW) * 256 + n0 + colw) * 8;
        gl16(Whi_g + so, &Wsd[buf][0][kgW][colw][0]);
        gl16(Wlo_g + so, &Wsd[buf][1][kgW][colw][0]);
    };
    auto loadA = [&](int k0, float4& v0, float4& v1) {
        const float* ap = A + (size_t)(m0 + sm) * 256 + k0 + klo;
        v0 = *(const float4*)ap;
        v1 = *(const float4*)(ap + 16);
    };
    auto writeA = [&](int buf, const float4 v0, const float4 v1) {
        uint2 h, lo;
        split4(v0, h, lo);
        *(uint2*)&As[buf][0][kg0][sm][sub0] = h;
        *(uint2*)&As[buf][1][kg0][sm][sub0] = lo;
        split4(v1, h, lo);
        *(uint2*)&As[buf][0][kg0 + 2][sm][sub0] = h;
        *(uint2*)&As[buf][1][kg0 + 2][sm][sub0] = lo;
    };

    {
        float4 p0, p1;
        loadA(0, p0, p1);
        stageW(0, 0);
        writeA(0, p0, p1);
    }
    for (int t = 0; t < 8; ++t) {
        const int cur = t & 1, nxt = cur ^ 1;
        __syncthreads();
        const bool pre = (t + 1 < 8);
        float4 nv0, nv1;
        if (pre) {
            loadA((t + 1) * 32, nv0, nv1);
            stageW((t + 1) * 32, nxt);
        }
        short8 ah[4], am[4];
#pragma unroll
        for (int i = 0; i < 4; ++i) {
            const int row = wm * 64 + i * 16 + lr;
            ah[i] = *(const short8*)&As[cur][0][kq][row][0];
            am[i] = *(const short8*)&As[cur][1][kq][row][0];
        }
#pragma unroll
        for (int j = 0; j < 2; ++j) {
            const int col = wn * 32 + j * 16 + lr;
            const short8 wh = *(const short8*)&Wsd[cur][0][kq][col][0];
            const short8 wl = *(const short8*)&Wsd[cur][1][kq][col][0];
#pragma unroll
            for (int i = 0; i < 4; ++i) {
                acc[i][j] = __builtin_amdgcn_mfma_f32_16x16x32_bf16(ah[i], wh, acc[i][j], 0, 0, 0);
                acc[i][j] = __builtin_amdgcn_mfma_f32_16x16x32_bf16(ah[i], wl, acc[i][j], 0, 0, 0);
                acc[i][j] = __builtin_amdgcn_mfma_f32_16x16x32_bf16(am[i], wh, acc[i][j], 0, 0, 0);
            }
        }
        if (pre) writeA(nxt, nv0, nv1);
    }
#pragma unroll
    for (int j = 0; j < 2; ++j) {
        const int col = n0 + wn * 32 + j * 16 + lr;
        const float bv = bias[col];
#pragma unroll
        for (int i = 0; i < 4; ++i) {
#pragma unroll
            for (int r = 0; r < 4; ++r) {
                const int row = m0 + wm * 64 + i * 16 + kq * 4 + r;
                const float o = acc[i][j][r] + bv;
                out0[(size_t)row * 256 + col] = o;
                out1[(size_t)row * 256 + col] = o;
            }
        }
    }
}

// ---------------- chunked complex scan, 3 passes ----------------
__global__ void scan_p1(const float* __restrict__ Bu, const float* __restrict__ dt,
                        const float* __restrict__ Lre, const float* __restrict__ Lim,
                        const float* __restrict__ ldl,
                        float* __restrict__ Ard, float* __restrict__ Erd) {
    const int c = blockIdx.x % NCHUNK, b = blockIdx.x / NCHUNK;
    const int p = threadIdx.x;
    const float lam_r = -expf(Lre[p]);
    const float lam_i = Lim[p];
    const float del = expf(ldl[p]);
    float Ar = 1.f, Ai = 0.f, xr = 0.f, xi = 0.f;
    const int n0 = c * CHLEN;
    for (int n = n0; n < n0 + CHLEN; ++n) {
        const float e = dt[b * NSEQ + n] * del;
        const float amag = expf(lam_r * e);
        float sn, cs;
        sincosf(lam_i * e, &sn, &cs);
        const float are = amag * cs, aim = amag * sn;
        const size_t tok = ((size_t)b * NSEQ + n) * 512;
        const float br = Bu[tok + p], bi = Bu[tok + 256 + p];
        const float nxr = are * xr - aim * xi + br;
        const float nxi = are * xi + aim * xr + bi;
        xr = nxr; xi = nxi;
        const float nAr = are * Ar - aim * Ai;
        const float nAi = are * Ai + aim * Ar;
        Ar = nAr; Ai = nAi;
    }
    const size_t o = ((size_t)b * NCHUNK + c) * 512;
    Ard[o + p] = Ar; Ard[o + 256 + p] = Ai;
    Erd[o + p] = xr; Erd[o + 256 + p] = xi;
}

__global__ void scan_p2(const float* __restrict__ Ard, const float* __restrict__ Erd,
                        const float* __restrict__ ire, const float* __restrict__ iim,
                        float* __restrict__ S) {
    const int b = blockIdx.x, p = threadIdx.x;
    float sr = ire[p], si = iim[p];
    for (int c = 0; c < NCHUNK; ++c) {
        const size_t o = ((size_t)b * NCHUNK + c) * 512;
        S[o + p] = sr; S[o + 256 + p] = si;
        const float ar = Ard[o + p], ai = Ard[o + 256 + p];
        const float er = Erd[o + p], ei = Erd[o + 256 + p];
        const float nr = ar * sr - ai * si + er;
        const float ni = ar * si + ai * sr + ei;
        sr = nr; si = ni;
    }
}

// pass 3: replay; write X_left only, pre-split bf16 hi/lo
__global__ void scan_p3(const float* __restrict__ Bu, const float* __restrict__ dt,
                        const float* __restrict__ Lre, const float* __restrict__ Lim,
                        const float* __restrict__ ldl, const float* __restrict__ S,
                        short* __restrict__ XlH, short* __restrict__ XlL) {
    const int c = blockIdx.x % NCHUNK, b = blockIdx.x / NCHUNK;
    const int p = threadIdx.x;
    const float lam_r = -expf(Lre[p]);
    const float lam_i = Lim[p];
    const float del = expf(ldl[p]);
    const size_t o = ((size_t)b * NCHUNK + c) * 512;
    float xr = S[o + p], xi = S[o + 256 + p];
    const int n0 = c * CHLEN;
    for (int n = n0; n < n0 + CHLEN; ++n) {
        const float e = dt[b * NSEQ + n] * del;
        const float amag = expf(lam_r * e);
        float sn, cs;
        sincosf(lam_i * e, &sn, &cs);
        const float are = amag * cs, aim = amag * sn;
        const size_t tok = ((size_t)b * NSEQ + n) * 512;
        const float br = Bu[tok + p], bi = Bu[tok + 256 + p];
        const float lr = are * xr - aim * xi;
        const float li = are * xi + aim * xr;
        u16 h, lo;
        split1(lr, h, lo); XlH[tok + p] = (short)h;       XlL[tok + p] = (short)lo;
        split1(li, h, lo); XlH[tok + 256 + p] = (short)h; XlL[tok + 256 + p] = (short)lo;
        xr = lr + br;
        xi = li + bi;
    }
}

extern "C" void kernel_launch(void* const* d_in, const int* in_sizes, int n_in,
                              void* d_out, int out_size, void* d_ws, size_t ws_size,
                              hipStream_t stream) {
    const float* x_payload = (const float*)d_in[0];
    const float* dt        = (const float*)d_in[1];
    const float* embed_W   = (const float*)d_in[2];
    const float* embed_b   = (const float*)d_in[3];
    const float* ln_scale  = (const float*)d_in[4];
    const float* ln_bias   = (const float*)d_in[5];
    const float* Lambda_re = (const float*)d_in[6];
    const float* Lambda_im = (const float*)d_in[7];
    const float* log_delta = (const float*)d_in[8];
    const float* B_re      = (const float*)d_in[9];
    const float* B_im      = (const float*)d_in[10];
    const float* C_re      = (const float*)d_in[11];
    const float* C_im      = (const float*)d_in[12];
    const float* W1        = (const float*)d_in[13];
    const float* b1        = (const float*)d_in[14];
    const float* W2        = (const float*)d_in[15];
    const float* b2        = (const float*)d_in[16];
    const float* init_re   = (const float*)d_in[17];
    const float* init_im   = (const float*)d_in[18];

    // shorts per (layer, precision)
    const size_t WB_SZ = 32 * 768 * 8;          // [Bre|Bim|Mr]
    const size_t WC_SZ = 64 * 256 * 8;          // [Cre; -Cim] stacked K=512
    const size_t W_SZ  = 32 * 256 * 8;
    const size_t wbytes = (W_SZ + NLAYER * (WB_SZ + WC_SZ + 2 * W_SZ)) * 2 * 2
                        + (size_t)NLAYER * 65536 * 4 + 65536;

    auto footprint = [&](int g) -> size_t {
        size_t T = (size_t)g * NSEQ;
        return T * 8192 + (size_t)g * NCHUNK * 512 * 4 * 3 + wbytes + 65536;
    };
    int g = BATCH;
    while (g > 1 && footprint(g) > ws_size) g >>= 1;

    char* ws = (char*)d_ws;
    size_t off = 0;
    auto alloc = [&](size_t bytes) {
        void* p = ws + off;
        off = (off + bytes + 255) & ~(size_t)255;
        return p;
    };
    const size_t T = (size_t)g * NSEQ;
    const int Tg = (int)T;
    const int MT = Tg / 128;
    float* u_r   = (float*)alloc(T * 1024);
    float* BuB   = (float*)alloc(T * 2048);
    short* vbufH = (short*)alloc(T * 512);
    short* vbufL = (short*)alloc(T * 512);
    short* XlH   = (short*)alloc(T * 1024);
    short* XlL   = (short*)alloc(T * 1024);
    float* ymr   = (float*)alloc(T * 1024);
    short* grH   = (short*)alloc(T * 512);
    short* grL   = (short*)alloc(T * 512);
    float* Ard   = (float*)alloc((size_t)g * NCHUNK * 512 * 4);
    float* Erd   = (float*)alloc((size_t)g * NCHUNK * 512 * 4);
    float* Sbuf  = (float*)alloc((size_t)g * NCHUNK * 512 * 4);
    short* embWh = (short*)alloc(W_SZ * 2);
    short* embWl = (short*)alloc(W_SZ * 2);
    short* WBh = (short*)alloc(NLAYER * WB_SZ * 2);
    short* WBl = (short*)alloc(NLAYER * WB_SZ * 2);
    short* WCh = (short*)alloc(NLAYER * WC_SZ * 2);
    short* WCl = (short*)alloc(NLAYER * WC_SZ * 2);
    short* W1h = (short*)alloc(NLAYER * W_SZ * 2);
    short* W1l = (short*)alloc(NLAYER * W_SZ * 2);
    short* W2h = (short*)alloc(NLAYER * W_SZ * 2);
    short* W2l = (short*)alloc(NLAYER * W_SZ * 2);
    float* MrF = (float*)alloc((size_t)NLAYER * 65536 * 4);
    short* glH = vbufH;   // vbuf dead after Bu GEMM; reuse for left gelu output
    short* glL = vbufL;

    // ---- one-shot weight prep: Mr GEMM, then split/transpose all weights ----
    mr_gemm<<<dim3(4, 4, 3), 256, 0, stream>>>(B_re, B_im, C_re, C_im, MrF);
    PrepArgs pa;
    int nj = 0;
    pa.j[nj++] = {embed_W, embWh, embWl, 256, 0, 1.f};
    for (int l = 0; l < NLAYER; ++l) {
        pa.j[nj++] = {B_re + (size_t)l * 65536, WBh + l * WB_SZ, WBl + l * WB_SZ, 768, 0, 1.f};
        pa.j[nj++] = {B_im + (size_t)l * 65536, WBh + l * WB_SZ, WBl + l * WB_SZ, 768, 256, 1.f};
        if (l < NLAYER - 1)
            pa.j[nj++] = {MrF + (size_t)l * 65536, WBh + l * WB_SZ, WBl + l * WB_SZ, 768, 512, 1.f};
        pa.j[nj++] = {C_re + (size_t)l * 65536, WCh + l * WC_SZ, WCl + l * WC_SZ, 256, 0, 1.f};
        pa.j[nj++] = {C_im + (size_t)l * 65536, WCh + l * WC_SZ + 32 * 256 * 8,
                      WCl + l * WC_SZ + 32 * 256 * 8, 256, 0, -1.f};
        pa.j[nj++] = {W1 + (size_t)l * 65536, W1h + l * W_SZ, W1l + l * W_SZ, 256, 0, 1.f};
        pa.j[nj++] = {W2 + (size_t)l * 65536, W2h + l * W_SZ, W2l + l * W_SZ, 256, 0, 1.f};
    }
    prep_w<<<dim3(32, nj), 256, 0, stream>>>(pa);

    for (int b0 = 0; b0 < BATCH; b0 += g) {
        const float* xg  = x_payload + (size_t)b0 * NSEQ * HDIM;
        const float* dtg = dt + (size_t)b0 * NSEQ;
        float* u_l = (float*)d_out + (size_t)b0 * NSEQ * HDIM;

        gemm_embed<<<dim3(MT, 2), 512, 0, stream>>>(xg, embWh, embWl, embed_b, u_r, u_l);

        for (int l = 0; l < NLAYER; ++l) {
            const bool wantR = (l < NLAYER - 1);
            const float* b1l = b1 + (size_t)l * 256;
            const float* b2l = b2 + (size_t)l * 256;
            const float* Lrl = Lambda_re + l * PDIM;
            const float* Lil = Lambda_im + l * PDIM;
            const float* ldll = log_delta + l * PDIM;
            const float* irl = init_re + l * PDIM;
            const float* iil = init_im + l * PDIM;
            const short* wbh = WBh + l * WB_SZ, *wbl = WBl + l * WB_SZ;
            const short* wch = WCh + l * WC_SZ, *wcl = WCl + l * WC_SZ;
            const short* w1hl = W1h + l * W_SZ, *w1ll = W1l + l * W_SZ;
            const short* w2hl = W2h + l * W_SZ, *w2ll = W2l + l * W_SZ;

            ln_wave<<<Tg / 4, 256, 0, stream>>>(u_r, ln_scale + l * HDIM, ln_bias + l * HDIM,
                                                vbufH, vbufL);
            // [Bu | ymr] = v_r @ [B_re | B_im | Mr]
            gemm_bu<<<dim3(MT, wantR ? 6 : 4), 512, 0, stream>>>(
                vbufH, vbufL, wbh, wbl, BuB, ymr);
            // chunked scan -> pre-split Xl
            scan_p1<<<g * NCHUNK, 256, 0, stream>>>(BuB, dtg, Lrl, Lil, ldll, Ard, Erd);
            scan_p2<<<g, 256, 0, stream>>>(Ard, Erd, irl, iil, Sbuf);
            scan_p3<<<g * NCHUNK, 256, 0, stream>>>(BuB, dtg, Lrl, Lil, ldll, Sbuf, XlH, XlL);
            // g_l = gelu(Xl @ C); g_r = gelu(Xl @ C + ymr)
            if (wantR) {
                gemm_c<1><<<dim3(MT, 2), 512, 0, stream>>>(XlH, XlL, wch, wcl, ymr,
                                                           glH, glL, grH, grL);
                glu_dma<<<dim3(MT, 4, 2), 512, 0, stream>>>(grH, grL, u_r, glH, glL, u_l,
                                                            w1hl, w1ll, w2hl, w2ll,
                                                            b1l, b2l, 0);
            } else {
                gemm_c<0><<<dim3(MT, 2), 512, 0, stream>>>(XlH, XlL, wch, wcl, ymr,
                                                           glH, glL, nullptr, nullptr);
                glu_dma<<<dim3(MT, 4, 1), 512, 0, stream>>>(glH, glL, u_l, glH, glL, u_l,
                                                            w1hl, w1ll, w2hl, w2ll,
                                                            b1l, b2l, 1);
            }
        }
    }
}

// Round 8
// 1208.047 us; speedup vs baseline: 1.1332x; 1.1332x over previous
//
#include <hip/hip_runtime.h>

#define NSEQ 2048
#define BATCH 16
#define HDIM 256
#define PDIM 256
#define NLAYER 4
#define NCHUNK 64
#define CHLEN (NSEQ / NCHUNK)   // 32

typedef __attribute__((ext_vector_type(8))) short short8;
typedef __attribute__((ext_vector_type(4))) float f32x4;
typedef unsigned int u32;
typedef unsigned short u16;

// gelu(tanh approx) == x * sigmoid(2z); native exp
__device__ __forceinline__ float gelu_tanh(float x) {
    const float z2 = 1.5957691216057308f * (x + 0.044715f * x * x * x);
    return x / (1.f + __expf(-z2));
}

__device__ __forceinline__ unsigned cvt_pk_bf16(float a, float b) {
    unsigned r;
    asm("v_cvt_pk_bf16_f32 %0, %1, %2" : "=v"(r) : "v"(a), "v"(b));
    return r;
}
__device__ __forceinline__ float bflo(unsigned u) { return __uint_as_float(u << 16); }
__device__ __forceinline__ float bfhi(unsigned u) { return __uint_as_float(u & 0xffff0000u); }

__device__ __forceinline__ void split4(const float4 v, uint2& h, uint2& l) {
    h.x = cvt_pk_bf16(v.x, v.y);
    h.y = cvt_pk_bf16(v.z, v.w);
    l.x = cvt_pk_bf16(v.x - bflo(h.x), v.y - bfhi(h.x));
    l.y = cvt_pk_bf16(v.z - bflo(h.y), v.w - bfhi(h.y));
}
__device__ __forceinline__ void split1(float v, u16& h, u16& lo) {
    const unsigned hp = cvt_pk_bf16(v, v);
    h = (u16)hp;
    const float res = v - __uint_as_float((hp & 0xffffu) << 16);
    lo = (u16)cvt_pk_bf16(res, res);
}

typedef __attribute__((address_space(1))) const u32 gu32;
typedef __attribute__((address_space(3))) u32 lu32;
__device__ __forceinline__ void gl16(const void* g, void* l) {
    __builtin_amdgcn_global_load_lds((gu32*)g, (lu32*)l, 16, 0, 0);
}

// ---------------- Mr = B_re@C_re - B_im@C_im (per layer), fp32 vector GEMM ----------------
__global__ __launch_bounds__(256) void mr_gemm(const float* __restrict__ Bre_g,
                                               const float* __restrict__ Bim_g,
                                               const float* __restrict__ Cre_g,
                                               const float* __restrict__ Cim_g,
                                               float* __restrict__ MrF) {
    const size_t lofs = (size_t)blockIdx.z * 65536;
    const float* Ar = Bre_g + lofs;
    const float* Ai = Bim_g + lofs;
    const float* Wr = Cre_g + lofs;
    const float* Wi = Cim_g + lofs;
    float* out = MrF + lofs;
    __shared__ float Asr[32][68], Asi[32][68], Wsr[32][68], Wsi[32][68];
    const int m0 = blockIdx.x << 6, n0 = blockIdx.y << 6;
    const int tx = threadIdx.x & 15, ty = threadIdx.x >> 4;
    const int ar = threadIdx.x >> 3, ak = (threadIdx.x & 7) << 2;
    const int wk = threadIdx.x >> 4, wn = (threadIdx.x & 15) << 2;
    float acc[4][4] = {};
    for (int k0 = 0; k0 < 256; k0 += 32) {
#pragma unroll
        for (int it = 0; it < 2; ++it) {
            const int r = (it << 5) + ar;
            float4 v = *(const float4*)&Ar[(size_t)(m0 + r) * 256 + k0 + ak];
            Asr[ak + 0][r] = v.x; Asr[ak + 1][r] = v.y; Asr[ak + 2][r] = v.z; Asr[ak + 3][r] = v.w;
            v = *(const float4*)&Ai[(size_t)(m0 + r) * 256 + k0 + ak];
            Asi[ak + 0][r] = v.x; Asi[ak + 1][r] = v.y; Asi[ak + 2][r] = v.z; Asi[ak + 3][r] = v.w;
        }
#pragma unroll
        for (int it = 0; it < 2; ++it) {
            const int k = (it << 4) + wk;
            *(float4*)&Wsr[k][wn] = *(const float4*)&Wr[(size_t)(k0 + k) * 256 + n0 + wn];
            *(float4*)&Wsi[k][wn] = *(const float4*)&Wi[(size_t)(k0 + k) * 256 + n0 + wn];
        }
        __syncthreads();
#pragma unroll 8
        for (int k = 0; k < 32; ++k) {
            const float4 a_r = *(const float4*)&Asr[k][ty << 2];
            const float4 a_i = *(const float4*)&Asi[k][ty << 2];
            const float4 w_r = *(const float4*)&Wsr[k][tx << 2];
            const float4 w_i = *(const float4*)&Wsi[k][tx << 2];
            const float aar[4] = {a_r.x, a_r.y, a_r.z, a_r.w};
            const float aai[4] = {a_i.x, a_i.y, a_i.z, a_i.w};
            const float wwr[4] = {w_r.x, w_r.y, w_r.z, w_r.w};
            const float wwi[4] = {w_i.x, w_i.y, w_i.z, w_i.w};
#pragma unroll
            for (int i = 0; i < 4; ++i)
#pragma unroll
                for (int j = 0; j < 4; ++j)
                    acc[i][j] += aar[i] * wwr[j] - aai[i] * wwi[j];
        }
        __syncthreads();
    }
#pragma unroll
    for (int i = 0; i < 4; ++i) {
        float4 o = {acc[i][0], acc[i][1], acc[i][2], acc[i][3]};
        *(float4*)&out[(size_t)(m0 + (ty << 2) + i) * 256 + n0 + (tx << 2)] = o;
    }
}

// ---------------- weight prep: fp32 (K,256) -> split bf16 [k/8][ldn][8] ----------------
struct PrepJob { const float* src; short* dhi; short* dlo; int ldn; int colofs; float sgn; };
struct PrepArgs { PrepJob j[28]; };

__global__ void prep_w(PrepArgs a) {
    const PrepJob jb = a.j[blockIdx.y];
    __shared__ float t[8][256];
    const int kg = blockIdx.x, tid = threadIdx.x;
    const int r = tid >> 5, c = (tid & 31) * 8;
    const float* src = jb.src + (size_t)(kg * 8 + r) * 256 + c;
    *(float4*)&t[r][c]     = *(const float4*)src;
    *(float4*)&t[r][c + 4] = *(const float4*)(src + 4);
    __syncthreads();
    const int n = tid;
    float x[8];
#pragma unroll
    for (int q = 0; q < 8; ++q) x[q] = t[q][n] * jb.sgn;
    uint4 h, l;
    h.x = cvt_pk_bf16(x[0], x[1]); h.y = cvt_pk_bf16(x[2], x[3]);
    h.z = cvt_pk_bf16(x[4], x[5]); h.w = cvt_pk_bf16(x[6], x[7]);
    l.x = cvt_pk_bf16(x[0] - bflo(h.x), x[1] - bfhi(h.x));
    l.y = cvt_pk_bf16(x[2] - bflo(h.y), x[3] - bfhi(h.y));
    l.z = cvt_pk_bf16(x[4] - bflo(h.z), x[5] - bfhi(h.z));
    l.w = cvt_pk_bf16(x[6] - bflo(h.w), x[7] - bfhi(h.w));
    const size_t o = ((size_t)kg * jb.ldn + jb.colofs + n) * 8;
    *(uint4*)&jb.dhi[o] = h;
    *(uint4*)&jb.dlo[o] = l;
}

// ---------------- LayerNorm: one wave per token, pre-split bf16 output ----------------
__global__ void ln_wave(const float* __restrict__ u, const float* __restrict__ sc,
                        const float* __restrict__ bs,
                        short* __restrict__ outH, short* __restrict__ outL) {
    const int lane = threadIdx.x & 63;
    const int w = threadIdx.x >> 6;
    const size_t tok = (size_t)blockIdx.x * 4 + w;
    const size_t base = tok * 256 + (size_t)lane * 4;
    const float4 x = *(const float4*)&u[base];
    float s = x.x + x.y + x.z + x.w;
#pragma unroll
    for (int off = 32; off; off >>= 1) s += __shfl_xor(s, off, 64);
    const float mean = s * (1.f / 256.f);
    const float dx = x.x - mean, dy = x.y - mean, dz = x.z - mean, dw = x.w - mean;
    float v = dx * dx + dy * dy + dz * dz + dw * dw;
#pragma unroll
    for (int off = 32; off; off >>= 1) v += __shfl_xor(v, off, 64);
    const float rstd = rsqrtf(v * (1.f / 256.f) + 1e-5f);
    const float4 s4 = *(const float4*)&sc[lane * 4];
    const float4 b4 = *(const float4*)&bs[lane * 4];
    float4 o;
    o.x = dx * rstd * s4.x + b4.x;
    o.y = dy * rstd * s4.y + b4.y;
    o.z = dz * rstd * s4.z + b4.z;
    o.w = dw * rstd * s4.w + b4.w;
    uint2 h, lo;
    split4(o, h, lo);
    *(uint2*)&outH[base] = h;
    *(uint2*)&outL[base] = lo;
}

// ---------------- Bu+ymr GEMM: A(v_r) reg-staged, W gl16, N up to 768 ----------------
__global__ __launch_bounds__(512, 4) void gemm_bu(
    const short* __restrict__ AH, const short* __restrict__ AL,
    const short* __restrict__ Whi_g, const short* __restrict__ Wlo_g,
    float* __restrict__ outBu, float* __restrict__ outY) {
    __shared__ short AsH[2][128 * 32], AsL[2][128 * 32];
    __shared__ short Wh[2][4 * 128 * 8], Wl[2][4 * 128 * 8];
    const int tid = threadIdx.x;
    const int m0 = blockIdx.x << 7, n0 = blockIdx.y << 7;
    const int wid = tid >> 6, l = tid & 63;
    const int wm = wid >> 2, wn = wid & 3;
    const int kq = l >> 4, lr = l & 15;
    const int sm = tid >> 2, sc = tid & 3;
    const int wslot = sc ^ ((sm >> 1) & 3);
    const int kgW = (tid >> 7) & 3, colw = tid & 127;

    f32x4 acc[4][2];
#pragma unroll
    for (int i = 0; i < 4; ++i)
#pragma unroll
        for (int j = 0; j < 2; ++j) acc[i][j] = {0.f, 0.f, 0.f, 0.f};

    auto stageW = [&](int k0, int buf) {
        const size_t so = ((size_t)((k0 >> 3) + kgW) * 768 + n0 + colw) * 8;
        gl16(Whi_g + so, &Wh[buf][(kgW * 128 + colw) * 8]);
        gl16(Wlo_g + so, &Wl[buf][(kgW * 128 + colw) * 8]);
    };
    auto loadA = [&](int k0, uint4& h, uint4& lo) {
        const size_t ab = (size_t)(m0 + sm) * 256 + k0 + sc * 8;
        h  = *(const uint4*)&AH[ab];
        lo = *(const uint4*)&AL[ab];
    };
    auto writeA = [&](int buf, const uint4 h, const uint4 lo) {
        const int cell = (sm * 4 + wslot) * 8;
        *(uint4*)&AsH[buf][cell] = h;
        *(uint4*)&AsL[buf][cell] = lo;
    };

    {
        uint4 p0, p1;
        loadA(0, p0, p1);
        stageW(0, 0);
        writeA(0, p0, p1);
    }
    const int sw = (lr >> 1) & 3;
    for (int t = 0; t < 8; ++t) {
        const int cur = t & 1, nxt = cur ^ 1;
        __syncthreads();
        const bool pre = (t + 1 < 8);
        uint4 nh, nl;
        if (pre) {
            loadA((t + 1) * 32, nh, nl);
            stageW((t + 1) * 32, nxt);
        }
        short8 ah[4], am[4];
#pragma unroll
        for (int i = 0; i < 4; ++i) {
            const int r = wm * 64 + i * 16 + lr;
            const int cell = (r * 4 + (kq ^ sw)) * 8;
            ah[i] = *(const short8*)&AsH[cur][cell];
            am[i] = *(const short8*)&AsL[cur][cell];
        }
#pragma unroll
        for (int j = 0; j < 2; ++j) {
            const int col = wn * 32 + j * 16 + lr;
            const short8 wh = *(const short8*)&Wh[cur][(kq * 128 + col) * 8];
            const short8 wl = *(const short8*)&Wl[cur][(kq * 128 + col) * 8];
#pragma unroll
            for (int i = 0; i < 4; ++i) {
                acc[i][j] = __builtin_amdgcn_mfma_f32_16x16x32_bf16(ah[i], wh, acc[i][j], 0, 0, 0);
                acc[i][j] = __builtin_amdgcn_mfma_f32_16x16x32_bf16(ah[i], wl, acc[i][j], 0, 0, 0);
                acc[i][j] = __builtin_amdgcn_mfma_f32_16x16x32_bf16(am[i], wh, acc[i][j], 0, 0, 0);
            }
        }
        if (pre) writeA(nxt, nh, nl);
    }
    const bool isY = (blockIdx.y >= 4);
#pragma unroll
    for (int j = 0; j < 2; ++j) {
        const int col = n0 + wn * 32 + j * 16 + lr;
#pragma unroll
        for (int i = 0; i < 4; ++i) {
#pragma unroll
            for (int r = 0; r < 4; ++r) {
                const int row = m0 + wm * 64 + i * 16 + kq * 4 + r;
                const float o = acc[i][j][r];
                if (isY) outY[(size_t)row * 256 + (col - 512)] = o;
                else     outBu[(size_t)row * 512 + col] = o;
            }
        }
    }
}

// ---------------- C GEMM (K=512, A=Xl): g_l split; g_r PACKED into ymr slots ----------------
template <int WANT_R>
__global__ __launch_bounds__(512, 4) void gemm_c(
    const short* __restrict__ AH, const short* __restrict__ AL,
    const short* __restrict__ Whi_g, const short* __restrict__ Wlo_g,
    float* ymr,                       // in: fp32 ymr; out (WANT_R): packed bf16 g_r (NO restrict)
    short* __restrict__ glH, short* __restrict__ glL) {
    __shared__ short AsH[2][128 * 32], AsL[2][128 * 32];
    __shared__ short Wh[2][4 * 128 * 8], Wl[2][4 * 128 * 8];
    const int tid = threadIdx.x;
    const int m0 = blockIdx.x << 7, n0 = blockIdx.y << 7;
    const int wid = tid >> 6, l = tid & 63;
    const int wm = wid >> 2, wn = wid & 3;
    const int kq = l >> 4, lr = l & 15;
    const int sm = tid >> 2, sc = tid & 3;
    const int wslot = sc ^ ((sm >> 1) & 3);
    const int kgW = (tid >> 7) & 3, colw = tid & 127;

    f32x4 acc[4][2];
#pragma unroll
    for (int i = 0; i < 4; ++i)
#pragma unroll
        for (int j = 0; j < 2; ++j) acc[i][j] = {0.f, 0.f, 0.f, 0.f};

    auto stageW = [&](int k0, int buf) {
        const size_t so = ((size_t)((k0 >> 3) + kgW) * 256 + n0 + colw) * 8;
        gl16(Whi_g + so, &Wh[buf][(kgW * 128 + colw) * 8]);
        gl16(Wlo_g + so, &Wl[buf][(kgW * 128 + colw) * 8]);
    };
    auto loadA = [&](int k0, uint4& h, uint4& lo) {
        const size_t ab = (size_t)(m0 + sm) * 512 + k0 + sc * 8;
        h  = *(const uint4*)&AH[ab];
        lo = *(const uint4*)&AL[ab];
    };
    auto writeA = [&](int buf, const uint4 h, const uint4 lo) {
        const int cell = (sm * 4 + wslot) * 8;
        *(uint4*)&AsH[buf][cell] = h;
        *(uint4*)&AsL[buf][cell] = lo;
    };

    {
        uint4 p0, p1;
        loadA(0, p0, p1);
        stageW(0, 0);
        writeA(0, p0, p1);
    }
    const int sw = (lr >> 1) & 3;
    for (int t = 0; t < 16; ++t) {
        const int cur = t & 1, nxt = cur ^ 1;
        __syncthreads();
        const bool pre = (t + 1 < 16);
        uint4 nh, nl;
        if (pre) {
            loadA((t + 1) * 32, nh, nl);
            stageW((t + 1) * 32, nxt);
        }
        short8 ah[4], am[4];
#pragma unroll
        for (int i = 0; i < 4; ++i) {
            const int r = wm * 64 + i * 16 + lr;
            const int cell = (r * 4 + (kq ^ sw)) * 8;
            ah[i] = *(const short8*)&AsH[cur][cell];
            am[i] = *(const short8*)&AsL[cur][cell];
        }
#pragma unroll
        for (int j = 0; j < 2; ++j) {
            const int col = wn * 32 + j * 16 + lr;
            const short8 wh = *(const short8*)&Wh[cur][(kq * 128 + col) * 8];
            const short8 wl = *(const short8*)&Wl[cur][(kq * 128 + col) * 8];
#pragma unroll
            for (int i = 0; i < 4; ++i) {
                acc[i][j] = __builtin_amdgcn_mfma_f32_16x16x32_bf16(ah[i], wh, acc[i][j], 0, 0, 0);
                acc[i][j] = __builtin_amdgcn_mfma_f32_16x16x32_bf16(ah[i], wl, acc[i][j], 0, 0, 0);
                acc[i][j] = __builtin_amdgcn_mfma_f32_16x16x32_bf16(am[i], wh, acc[i][j], 0, 0, 0);
            }
        }
        if (pre) writeA(nxt, nh, nl);
    }
#pragma unroll
    for (int j = 0; j < 2; ++j) {
        const int col = n0 + wn * 32 + j * 16 + lr;
#pragma unroll
        for (int i = 0; i < 4; ++i) {
#pragma unroll
            for (int r = 0; r < 4; ++r) {
                const int row = m0 + wm * 64 + i * 16 + kq * 4 + r;
                const size_t o = (size_t)row * 256 + col;
                const float y = acc[i][j][r];
                u16 h, lo;
                split1(gelu_tanh(y), h, lo);
                glH[o] = (short)h; glL[o] = (short)lo;
                if constexpr (WANT_R) {
                    const float yr = y + ymr[o];          // read fp32 ymr
                    split1(gelu_tanh(yr), h, lo);
                    ((u32*)ymr)[o] = (u32)h | ((u32)lo << 16);   // overwrite same slot: packed g_r
                }
            }
        }
    }
}

// ---------------- fused GLU GEMM, z-selected stream ----------------
// PK0: z==0 stream A is packed (h|l<<16 per elem); z==1 always split arrays.
template <int PK0>
__global__ __launch_bounds__(512, 4) void glu_dma(
    const u32* __restrict__ A0pk, const short* __restrict__ A0H, const short* __restrict__ A0L,
    float* __restrict__ u0,
    const short* __restrict__ A1H, const short* __restrict__ A1L, float* __restrict__ u1,
    const short* __restrict__ W1h, const short* __restrict__ W1l,
    const short* __restrict__ W2h, const short* __restrict__ W2l,
    const float* __restrict__ b1, const float* __restrict__ b2, int zero0) {
    __shared__ short AsH[2][128 * 32], AsL[2][128 * 32];
    __shared__ short Ws[2][4][4 * 64 * 8];
    const int z = blockIdx.z;
    const bool usePk = PK0 && (z == 0);
    const short* AH = z ? A1H : A0H;
    const short* AL = z ? A1L : A0L;
    float* u = z ? u1 : u0;
    const int tid = threadIdx.x;
    const int m0 = blockIdx.x << 7, n0 = blockIdx.y << 6;
    const int wid = tid >> 6, l = tid & 63;
    const int wm = wid >> 2, wn = wid & 3;
    const int kq = l >> 4, lr = l & 15;
    const int sm = tid >> 2, sc = tid & 3;
    const int wslot = sc ^ ((sm >> 1) & 3);
    const int kgW = (tid >> 6) & 3, colw = tid & 63, selLo = (tid >> 8) & 1;

    f32x4 acc1[4], acc2[4];
#pragma unroll
    for (int i = 0; i < 4; ++i) {
        acc1[i] = {0.f, 0.f, 0.f, 0.f};
        acc2[i] = {0.f, 0.f, 0.f, 0.f};
    }

    auto stageW = [&](int k0, int buf) {
        const size_t so = ((size_t)((k0 >> 3) + kgW) * 256 + n0 + colw) * 8;
        const short* s1 = selLo ? W1l : W1h;
        const short* s2 = selLo ? W2l : W2h;
        gl16(s1 + so, &Ws[buf][selLo][(kgW * 64 + colw) * 8]);
        gl16(s2 + so, &Ws[buf][2 + selLo][(kgW * 64 + colw) * 8]);
    };
    auto loadA = [&](int k0, uint4& h, uint4& lo) {
        const size_t ab = (size_t)(m0 + sm) * 256 + k0 + sc * 8;
        if (usePk) {
            const uint4 p0 = *(const uint4*)&A0pk[ab];
            const uint4 p1 = *(const uint4*)&A0pk[ab + 4];
            h.x = (p0.x & 0xFFFFu) | (p0.y << 16);
            lo.x = (p0.x >> 16)    | (p0.y & 0xFFFF0000u);
            h.y = (p0.z & 0xFFFFu) | (p0.w << 16);
            lo.y = (p0.z >> 16)    | (p0.w & 0xFFFF0000u);
            h.z = (p1.x & 0xFFFFu) | (p1.y << 16);
            lo.z = (p1.x >> 16)    | (p1.y & 0xFFFF0000u);
            h.w = (p1.z & 0xFFFFu) | (p1.w << 16);
            lo.w = (p1.z >> 16)    | (p1.w & 0xFFFF0000u);
        } else {
            h  = *(const uint4*)&AH[ab];
            lo = *(const uint4*)&AL[ab];
        }
    };
    auto writeA = [&](int buf, const uint4 h, const uint4 lo) {
        const int cell = (sm * 4 + wslot) * 8;
        *(uint4*)&AsH[buf][cell] = h;
        *(uint4*)&AsL[buf][cell] = lo;
    };

    {
        uint4 p0, p1;
        loadA(0, p0, p1);
        stageW(0, 0);
        writeA(0, p0, p1);
    }
    const int sw = (lr >> 1) & 3;
    for (int t = 0; t < 8; ++t) {
        const int cur = t & 1, nxt = cur ^ 1;
        __syncthreads();
        const bool pre = (t + 1 < 8);
        uint4 nh, nl;
        if (pre) {
            loadA((t + 1) * 32, nh, nl);
            stageW((t + 1) * 32, nxt);
        }
        short8 ah[4], am[4];
#pragma unroll
        for (int i = 0; i < 4; ++i) {
            const int r = wm * 64 + i * 16 + lr;
            const int cell = (r * 4 + (kq ^ sw)) * 8;
            ah[i] = *(const short8*)&AsH[cur][cell];
            am[i] = *(const short8*)&AsL[cur][cell];
        }
        {
            const int col = wn * 16 + lr;
            const short8 w1h = *(const short8*)&Ws[cur][0][(kq * 64 + col) * 8];
            const short8 w1l = *(const short8*)&Ws[cur][1][(kq * 64 + col) * 8];
            const short8 w2h = *(const short8*)&Ws[cur][2][(kq * 64 + col) * 8];
            const short8 w2l = *(const short8*)&Ws[cur][3][(kq * 64 + col) * 8];
#pragma unroll
            for (int i = 0; i < 4; ++i) {
                acc1[i] = __builtin_amdgcn_mfma_f32_16x16x32_bf16(ah[i], w1h, acc1[i], 0, 0, 0);
                acc1[i] = __builtin_amdgcn_mfma_f32_16x16x32_bf16(ah[i], w1l, acc1[i], 0, 0, 0);
                acc1[i] = __builtin_amdgcn_mfma_f32_16x16x32_bf16(am[i], w1h, acc1[i], 0, 0, 0);
                acc2[i] = __builtin_amdgcn_mfma_f32_16x16x32_bf16(ah[i], w2h, acc2[i], 0, 0, 0);
                acc2[i] = __builtin_amdgcn_mfma_f32_16x16x32_bf16(ah[i], w2l, acc2[i], 0, 0, 0);
                acc2[i] = __builtin_amdgcn_mfma_f32_16x16x32_bf16(am[i], w2h, acc2[i], 0, 0, 0);
            }
        }
        if (pre) writeA(nxt, nh, nl);
    }
    {
        const int col = n0 + wn * 16 + lr;
        const float c1 = b1[col], c2 = b2[col];
#pragma unroll
        for (int i = 0; i < 4; ++i) {
#pragma unroll
            for (int r = 0; r < 4; ++r) {
                const int row = m0 + wm * 64 + i * 16 + kq * 4 + r;
                const size_t o = (size_t)row * 256 + col;
                if (zero0 && ((row & (NSEQ - 1)) == 0)) {
                    u[o] = 0.f;
                } else {
                    const float t1 = acc1[i][r] + c1;
                    const float t2 = acc2[i][r] + c2;
                    u[o] += t1 * (1.f / (1.f + __expf(-t2)));
                }
            }
        }
    }
}

// ---------------- embed GEMM: fp32 A (input), split in-kernel (runs once) ----------------
__global__ __launch_bounds__(512, 4) void gemm_embed(
    const float* __restrict__ A,
    const short* __restrict__ Whi_g, const short* __restrict__ Wlo_g,
    const float* __restrict__ bias,
    float* __restrict__ out0, float* __restrict__ out1) {
    __shared__ short As[2][2][4][128][8];
    __shared__ short Wsd[2][2][4][128][8];
    const int tid = threadIdx.x;
    const int m0 = blockIdx.x << 7, n0 = blockIdx.y << 7;
    const int wid = tid >> 6, l = tid & 63;
    const int wm = wid >> 2, wn = wid & 3;
    const int kq = l >> 4, lr = l & 15;
    const int sm = tid >> 2;
    const int klo = (tid & 3) * 4;
    const int kg0 = klo >> 3, sub0 = klo & 7;
    const int kgW = (tid >> 7) & 3, colw = tid & 127;

    f32x4 acc[4][2];
#pragma unroll
    for (int i = 0; i < 4; ++i)
#pragma unroll
        for (int j = 0; j < 2; ++j) acc[i][j] = {0.f, 0.f, 0.f, 0.f};

    auto stageW = [&](int k0, int buf) {
        const size_t so = ((size_t)((k0 >> 3) + kgW) * 256 + n0 + colw) * 8;
        gl16(Whi_g + so, &Wsd[buf][0][kgW][colw][0]);
        gl16(Wlo_g + so, &Wsd[buf][1][kgW][colw][0]);
    };
    auto loadA = [&](int k0, float4& v0, float4& v1) {
        const float* ap = A + (size_t)(m0 + sm) * 256 + k0 + klo;
        v0 = *(const float4*)ap;
        v1 = *(const float4*)(ap + 16);
    };
    auto writeA = [&](int buf, const float4 v0, const float4 v1) {
        uint2 h, lo;
        split4(v0, h, lo);
        *(uint2*)&As[buf][0][kg0][sm][sub0] = h;
        *(uint2*)&As[buf][1][kg0][sm][sub0] = lo;
        split4(v1, h, lo);
        *(uint2*)&As[buf][0][kg0 + 2][sm][sub0] = h;
        *(uint2*)&As[buf][1][kg0 + 2][sm][sub0] = lo;
    };

    {
        float4 p0, p1;
        loadA(0, p0, p1);
        stageW(0, 0);
        writeA(0, p0, p1);
    }
    for (int t = 0; t < 8; ++t) {
        const int cur = t & 1, nxt = cur ^ 1;
        __syncthreads();
        const bool pre = (t + 1 < 8);
        float4 nv0, nv1;
        if (pre) {
            loadA((t + 1) * 32, nv0, nv1);
            stageW((t + 1) * 32, nxt);
        }
        short8 ah[4], am[4];
#pragma unroll
        for (int i = 0; i < 4; ++i) {
            const int row = wm * 64 + i * 16 + lr;
            ah[i] = *(const short8*)&As[cur][0][kq][row][0];
            am[i] = *(const short8*)&As[cur][1][kq][row][0];
        }
#pragma unroll
        for (int j = 0; j < 2; ++j) {
            const int col = wn * 32 + j * 16 + lr;
            const short8 wh = *(const short8*)&Wsd[cur][0][kq][col][0];
            const short8 wl = *(const short8*)&Wsd[cur][1][kq][col][0];
#pragma unroll
            for (int i = 0; i < 4; ++i) {
                acc[i][j] = __builtin_amdgcn_mfma_f32_16x16x32_bf16(ah[i], wh, acc[i][j], 0, 0, 0);
                acc[i][j] = __builtin_amdgcn_mfma_f32_16x16x32_bf16(ah[i], wl, acc[i][j], 0, 0, 0);
                acc[i][j] = __builtin_amdgcn_mfma_f32_16x16x32_bf16(am[i], wh, acc[i][j], 0, 0, 0);
            }
        }
        if (pre) writeA(nxt, nv0, nv1);
    }
#pragma unroll
    for (int j = 0; j < 2; ++j) {
        const int col = n0 + wn * 32 + j * 16 + lr;
        const float bv = bias[col];
#pragma unroll
        for (int i = 0; i < 4; ++i) {
#pragma unroll
            for (int r = 0; r < 4; ++r) {
                const int row = m0 + wm * 64 + i * 16 + kq * 4 + r;
                const float o = acc[i][j][r] + bv;
                out0[(size_t)row * 256 + col] = o;
                out1[(size_t)row * 256 + col] = o;
            }
        }
    }
}

// ---------------- chunked complex scan, 3 passes ----------------
__global__ void scan_p1(const float* __restrict__ Bu, const float* __restrict__ dt,
                        const float* __restrict__ Lre, const float* __restrict__ Lim,
                        const float* __restrict__ ldl,
                        float* __restrict__ Ard, float* __restrict__ Erd) {
    const int c = blockIdx.x % NCHUNK, b = blockIdx.x / NCHUNK;
    const int p = threadIdx.x;
    const float lam_r = -expf(Lre[p]);
    const float lam_i = Lim[p];
    const float del = expf(ldl[p]);
    float Ar = 1.f, Ai = 0.f, xr = 0.f, xi = 0.f;
    const int n0 = c * CHLEN;
    for (int n = n0; n < n0 + CHLEN; ++n) {
        const float e = dt[b * NSEQ + n] * del;
        const float amag = expf(lam_r * e);
        float sn, cs;
        sincosf(lam_i * e, &sn, &cs);
        const float are = amag * cs, aim = amag * sn;
        const size_t tok = ((size_t)b * NSEQ + n) * 512;
        const float br = Bu[tok + p], bi = Bu[tok + 256 + p];
        const float nxr = are * xr - aim * xi + br;
        const float nxi = are * xi + aim * xr + bi;
        xr = nxr; xi = nxi;
        const float nAr = are * Ar - aim * Ai;
        const float nAi = are * Ai + aim * Ar;
        Ar = nAr; Ai = nAi;
    }
    const size_t o = ((size_t)b * NCHUNK + c) * 512;
    Ard[o + p] = Ar; Ard[o + 256 + p] = Ai;
    Erd[o + p] = xr; Erd[o + 256 + p] = xi;
}

__global__ void scan_p2(const float* __restrict__ Ard, const float* __restrict__ Erd,
                        const float* __restrict__ ire, const float* __restrict__ iim,
                        float* __restrict__ S) {
    const int b = blockIdx.x, p = threadIdx.x;
    float sr = ire[p], si = iim[p];
    for (int c = 0; c < NCHUNK; ++c) {
        const size_t o = ((size_t)b * NCHUNK + c) * 512;
        S[o + p] = sr; S[o + 256 + p] = si;
        const float ar = Ard[o + p], ai = Ard[o + 256 + p];
        const float er = Erd[o + p], ei = Erd[o + 256 + p];
        const float nr = ar * sr - ai * si + er;
        const float ni = ar * si + ai * sr + ei;
        sr = nr; si = ni;
    }
}

// pass 3: replay; write X_left only, pre-split bf16 hi/lo
__global__ void scan_p3(const float* __restrict__ Bu, const float* __restrict__ dt,
                        const float* __restrict__ Lre, const float* __restrict__ Lim,
                        const float* __restrict__ ldl, const float* __restrict__ S,
                        short* __restrict__ XlH, short* __restrict__ XlL) {
    const int c = blockIdx.x % NCHUNK, b = blockIdx.x / NCHUNK;
    const int p = threadIdx.x;
    const float lam_r = -expf(Lre[p]);
    const float lam_i = Lim[p];
    const float del = expf(ldl[p]);
    const size_t o = ((size_t)b * NCHUNK + c) * 512;
    float xr = S[o + p], xi = S[o + 256 + p];
    const int n0 = c * CHLEN;
    for (int n = n0; n < n0 + CHLEN; ++n) {
        const float e = dt[b * NSEQ + n] * del;
        const float amag = expf(lam_r * e);
        float sn, cs;
        sincosf(lam_i * e, &sn, &cs);
        const float are = amag * cs, aim = amag * sn;
        const size_t tok = ((size_t)b * NSEQ + n) * 512;
        const float br = Bu[tok + p], bi = Bu[tok + 256 + p];
        const float lr = are * xr - aim * xi;
        const float li = are * xi + aim * xr;
        u16 h, lo;
        split1(lr, h, lo); XlH[tok + p] = (short)h;       XlL[tok + p] = (short)lo;
        split1(li, h, lo); XlH[tok + 256 + p] = (short)h; XlL[tok + 256 + p] = (short)lo;
        xr = lr + br;
        xi = li + bi;
    }
}

extern "C" void kernel_launch(void* const* d_in, const int* in_sizes, int n_in,
                              void* d_out, int out_size, void* d_ws, size_t ws_size,
                              hipStream_t stream) {
    const float* x_payload = (const float*)d_in[0];
    const float* dt        = (const float*)d_in[1];
    const float* embed_W   = (const float*)d_in[2];
    const float* embed_b   = (const float*)d_in[3];
    const float* ln_scale  = (const float*)d_in[4];
    const float* ln_bias   = (const float*)d_in[5];
    const float* Lambda_re = (const float*)d_in[6];
    const float* Lambda_im = (const float*)d_in[7];
    const float* log_delta = (const float*)d_in[8];
    const float* B_re      = (const float*)d_in[9];
    const float* B_im      = (const float*)d_in[10];
    const float* C_re      = (const float*)d_in[11];
    const float* C_im      = (const float*)d_in[12];
    const float* W1        = (const float*)d_in[13];
    const float* b1        = (const float*)d_in[14];
    const float* W2        = (const float*)d_in[15];
    const float* b2        = (const float*)d_in[16];
    const float* init_re   = (const float*)d_in[17];
    const float* init_im   = (const float*)d_in[18];

    const size_t WB_SZ = 32 * 768 * 8;          // shorts: [Bre|Bim|Mr]
    const size_t WC_SZ = 64 * 256 * 8;          // shorts: [Cre; -Cim] stacked K=512
    const size_t W_SZ  = 32 * 256 * 8;
    const size_t wbytes = (W_SZ + NLAYER * (WB_SZ + WC_SZ + 2 * W_SZ)) * 2 * 2
                        + (size_t)NLAYER * 65536 * 4 + 65536;

    // per-token: u_r 1024 + Bu 2048 + vbuf 1024 + Xl 2048 + ymr/gr 1024 = 7168 B
    auto footprint = [&](int g) -> size_t {
        size_t T = (size_t)g * NSEQ;
        return T * 7168 + (size_t)g * NCHUNK * 512 * 4 * 3 + wbytes + 65536;
    };
    int g = BATCH;
    while (g > 1 && footprint(g) > ws_size) g >>= 1;

    char* ws = (char*)d_ws;
    size_t off = 0;
    auto alloc = [&](size_t bytes) {
        void* p = ws + off;
        off = (off + bytes + 255) & ~(size_t)255;
        return p;
    };
    const size_t T = (size_t)g * NSEQ;
    const int Tg = (int)T;
    const int MT = Tg / 128;
    float* u_r   = (float*)alloc(T * 1024);
    float* BuB   = (float*)alloc(T * 2048);
    short* vbufH = (short*)alloc(T * 512);
    short* vbufL = (short*)alloc(T * 512);
    short* XlH   = (short*)alloc(T * 1024);
    short* XlL   = (short*)alloc(T * 1024);
    float* ymr   = (float*)alloc(T * 1024);     // fp32 ymr in; packed bf16 g_r out
    float* Ard   = (float*)alloc((size_t)g * NCHUNK * 512 * 4);
    float* Erd   = (float*)alloc((size_t)g * NCHUNK * 512 * 4);
    float* Sbuf  = (float*)alloc((size_t)g * NCHUNK * 512 * 4);
    short* embWh = (short*)alloc(W_SZ * 2);
    short* embWl = (short*)alloc(W_SZ * 2);
    short* WBh = (short*)alloc(NLAYER * WB_SZ * 2);
    short* WBl = (short*)alloc(NLAYER * WB_SZ * 2);
    short* WCh = (short*)alloc(NLAYER * WC_SZ * 2);
    short* WCl = (short*)alloc(NLAYER * WC_SZ * 2);
    short* W1h = (short*)alloc(NLAYER * W_SZ * 2);
    short* W1l = (short*)alloc(NLAYER * W_SZ * 2);
    short* W2h = (short*)alloc(NLAYER * W_SZ * 2);
    short* W2l = (short*)alloc(NLAYER * W_SZ * 2);
    float* MrF = (float*)alloc((size_t)NLAYER * 65536 * 4);
    short* glH = vbufH;   // vbuf dead after Bu GEMM; reuse for left gelu output
    short* glL = vbufL;

    // ---- one-shot weight prep: Mr GEMM, then split/transpose all weights ----
    mr_gemm<<<dim3(4, 4, 3), 256, 0, stream>>>(B_re, B_im, C_re, C_im, MrF);
    PrepArgs pa;
    int nj = 0;
    pa.j[nj++] = {embed_W, embWh, embWl, 256, 0, 1.f};
    for (int l = 0; l < NLAYER; ++l) {
        pa.j[nj++] = {B_re + (size_t)l * 65536, WBh + l * WB_SZ, WBl + l * WB_SZ, 768, 0, 1.f};
        pa.j[nj++] = {B_im + (size_t)l * 65536, WBh + l * WB_SZ, WBl + l * WB_SZ, 768, 256, 1.f};
        if (l < NLAYER - 1)
            pa.j[nj++] = {MrF + (size_t)l * 65536, WBh + l * WB_SZ, WBl + l * WB_SZ, 768, 512, 1.f};
        pa.j[nj++] = {C_re + (size_t)l * 65536, WCh + l * WC_SZ, WCl + l * WC_SZ, 256, 0, 1.f};
        pa.j[nj++] = {C_im + (size_t)l * 65536, WCh + l * WC_SZ + 32 * 256 * 8,
                      WCl + l * WC_SZ + 32 * 256 * 8, 256, 0, -1.f};
        pa.j[nj++] = {W1 + (size_t)l * 65536, W1h + l * W_SZ, W1l + l * W_SZ, 256, 0, 1.f};
        pa.j[nj++] = {W2 + (size_t)l * 65536, W2h + l * W_SZ, W2l + l * W_SZ, 256, 0, 1.f};
    }
    prep_w<<<dim3(32, nj), 256, 0, stream>>>(pa);

    for (int b0 = 0; b0 < BATCH; b0 += g) {
        const float* xg  = x_payload + (size_t)b0 * NSEQ * HDIM;
        const float* dtg = dt + (size_t)b0 * NSEQ;
        float* u_l = (float*)d_out + (size_t)b0 * NSEQ * HDIM;

        gemm_embed<<<dim3(MT, 2), 512, 0, stream>>>(xg, embWh, embWl, embed_b, u_r, u_l);

        for (int l = 0; l < NLAYER; ++l) {
            const bool wantR = (l < NLAYER - 1);
            const float* b1l = b1 + (size_t)l * 256;
            const float* b2l = b2 + (size_t)l * 256;
            const float* Lrl = Lambda_re + l * PDIM;
            const float* Lil = Lambda_im + l * PDIM;
            const float* ldll = log_delta + l * PDIM;
            const float* irl = init_re + l * PDIM;
            const float* iil = init_im + l * PDIM;
            const short* wbh = WBh + l * WB_SZ, *wbl = WBl + l * WB_SZ;
            const short* wch = WCh + l * WC_SZ, *wcl = WCl + l * WC_SZ;
            const short* w1hl = W1h + l * W_SZ, *w1ll = W1l + l * W_SZ;
            const short* w2hl = W2h + l * W_SZ, *w2ll = W2l + l * W_SZ;

            ln_wave<<<Tg / 4, 256, 0, stream>>>(u_r, ln_scale + l * HDIM, ln_bias + l * HDIM,
                                                vbufH, vbufL);
            gemm_bu<<<dim3(MT, wantR ? 6 : 4), 512, 0, stream>>>(
                vbufH, vbufL, wbh, wbl, BuB, ymr);
            scan_p1<<<g * NCHUNK, 256, 0, stream>>>(BuB, dtg, Lrl, Lil, ldll, Ard, Erd);
            scan_p2<<<g, 256, 0, stream>>>(Ard, Erd, irl, iil, Sbuf);
            scan_p3<<<g * NCHUNK, 256, 0, stream>>>(BuB, dtg, Lrl, Lil, ldll, Sbuf, XlH, XlL);
            if (wantR) {
                gemm_c<1><<<dim3(MT, 2), 512, 0, stream>>>(XlH, XlL, wch, wcl, ymr, glH, glL);
                glu_dma<1><<<dim3(MT, 4, 2), 512, 0, stream>>>(
                    (const u32*)ymr, nullptr, nullptr, u_r, glH, glL, u_l,
                    w1hl, w1ll, w2hl, w2ll, b1l, b2l, 0);
            } else {
                gemm_c<0><<<dim3(MT, 2), 512, 0, stream>>>(XlH, XlL, wch, wcl, ymr, glH, glL);
                glu_dma<0><<<dim3(MT, 4, 1), 512, 0, stream>>>(
                    nullptr, glH, glL, u_l, nullptr, nullptr, nullptr,
                    w1hl, w1ll, w2hl, w2ll, b1l, b2l, 1);
            }
        }
    }
}

// Round 9
// 1196.373 us; speedup vs baseline: 1.1442x; 1.0098x over previous
//
#include <hip/hip_runtime.h>

#define NSEQ 2048
#define BATCH 16
#define HDIM 256
#define PDIM 256
#define NLAYER 4
#define NCHUNK 64
#define CHLEN (NSEQ / NCHUNK)   // 32

typedef __attribute__((ext_vector_type(8))) short short8;
typedef __attribute__((ext_vector_type(4))) float f32x4;
typedef unsigned int u32;
typedef unsigned short u16;

// gelu(tanh approx) == x * sigmoid(2z); native exp
__device__ __forceinline__ float gelu_tanh(float x) {
    const float z2 = 1.5957691216057308f * (x + 0.044715f * x * x * x);
    return x / (1.f + __expf(-z2));
}

__device__ __forceinline__ unsigned cvt_pk_bf16(float a, float b) {
    unsigned r;
    asm("v_cvt_pk_bf16_f32 %0, %1, %2" : "=v"(r) : "v"(a), "v"(b));
    return r;
}
__device__ __forceinline__ float bflo(unsigned u) { return __uint_as_float(u << 16); }
__device__ __forceinline__ float bfhi(unsigned u) { return __uint_as_float(u & 0xffff0000u); }

__device__ __forceinline__ void split4(const float4 v, uint2& h, uint2& l) {
    h.x = cvt_pk_bf16(v.x, v.y);
    h.y = cvt_pk_bf16(v.z, v.w);
    l.x = cvt_pk_bf16(v.x - bflo(h.x), v.y - bfhi(h.x));
    l.y = cvt_pk_bf16(v.z - bflo(h.y), v.w - bfhi(h.y));
}
__device__ __forceinline__ void split1(float v, u16& h, u16& lo) {
    const unsigned hp = cvt_pk_bf16(v, v);
    h = (u16)hp;
    const float res = v - __uint_as_float((hp & 0xffffu) << 16);
    lo = (u16)cvt_pk_bf16(res, res);
}

typedef __attribute__((address_space(1))) const u32 gu32;
typedef __attribute__((address_space(3))) u32 lu32;
__device__ __forceinline__ void gl16(const void* g, void* l) {
    __builtin_amdgcn_global_load_lds((gu32*)g, (lu32*)l, 16, 0, 0);
}

// ---- manual phase-sync: never drain vmcnt at the barrier (T4 counted-vmcnt) ----
__device__ __forceinline__ void bar_top() {
    asm volatile("s_waitcnt lgkmcnt(0)" ::: "memory");   // my ds_writes visible
    __builtin_amdgcn_s_barrier();
    __builtin_amdgcn_sched_barrier(0);
}
__device__ __forceinline__ void wait_vm4() {
    asm volatile("s_waitcnt vmcnt(4)" ::: "memory");     // drain prev-phase W DMA only
    __builtin_amdgcn_sched_barrier(0);
}
__device__ __forceinline__ void wait_vm0() {
    asm volatile("s_waitcnt vmcnt(0)" ::: "memory");
    __builtin_amdgcn_sched_barrier(0);
}

// ---------------- Mr = B_re@C_re - B_im@C_im (per layer), fp32 vector GEMM ----------------
__global__ __launch_bounds__(256) void mr_gemm(const float* __restrict__ Bre_g,
                                               const float* __restrict__ Bim_g,
                                               const float* __restrict__ Cre_g,
                                               const float* __restrict__ Cim_g,
                                               float* __restrict__ MrF) {
    const size_t lofs = (size_t)blockIdx.z * 65536;
    const float* Ar = Bre_g + lofs;
    const float* Ai = Bim_g + lofs;
    const float* Wr = Cre_g + lofs;
    const float* Wi = Cim_g + lofs;
    float* out = MrF + lofs;
    __shared__ float Asr[32][68], Asi[32][68], Wsr[32][68], Wsi[32][68];
    const int m0 = blockIdx.x << 6, n0 = blockIdx.y << 6;
    const int tx = threadIdx.x & 15, ty = threadIdx.x >> 4;
    const int ar = threadIdx.x >> 3, ak = (threadIdx.x & 7) << 2;
    const int wk = threadIdx.x >> 4, wn = (threadIdx.x & 15) << 2;
    float acc[4][4] = {};
    for (int k0 = 0; k0 < 256; k0 += 32) {
#pragma unroll
        for (int it = 0; it < 2; ++it) {
            const int r = (it << 5) + ar;
            float4 v = *(const float4*)&Ar[(size_t)(m0 + r) * 256 + k0 + ak];
            Asr[ak + 0][r] = v.x; Asr[ak + 1][r] = v.y; Asr[ak + 2][r] = v.z; Asr[ak + 3][r] = v.w;
            v = *(const float4*)&Ai[(size_t)(m0 + r) * 256 + k0 + ak];
            Asi[ak + 0][r] = v.x; Asi[ak + 1][r] = v.y; Asi[ak + 2][r] = v.z; Asi[ak + 3][r] = v.w;
        }
#pragma unroll
        for (int it = 0; it < 2; ++it) {
            const int k = (it << 4) + wk;
            *(float4*)&Wsr[k][wn] = *(const float4*)&Wr[(size_t)(k0 + k) * 256 + n0 + wn];
            *(float4*)&Wsi[k][wn] = *(const float4*)&Wi[(size_t)(k0 + k) * 256 + n0 + wn];
        }
        __syncthreads();
#pragma unroll 8
        for (int k = 0; k < 32; ++k) {
            const float4 a_r = *(const float4*)&Asr[k][ty << 2];
            const float4 a_i = *(const float4*)&Asi[k][ty << 2];
            const float4 w_r = *(const float4*)&Wsr[k][tx << 2];
            const float4 w_i = *(const float4*)&Wsi[k][tx << 2];
            const float aar[4] = {a_r.x, a_r.y, a_r.z, a_r.w};
            const float aai[4] = {a_i.x, a_i.y, a_i.z, a_i.w};
            const float wwr[4] = {w_r.x, w_r.y, w_r.z, w_r.w};
            const float wwi[4] = {w_i.x, w_i.y, w_i.z, w_i.w};
#pragma unroll
            for (int i = 0; i < 4; ++i)
#pragma unroll
                for (int j = 0; j < 4; ++j)
                    acc[i][j] += aar[i] * wwr[j] - aai[i] * wwi[j];
        }
        __syncthreads();
    }
#pragma unroll
    for (int i = 0; i < 4; ++i) {
        float4 o = {acc[i][0], acc[i][1], acc[i][2], acc[i][3]};
        *(float4*)&out[(size_t)(m0 + (ty << 2) + i) * 256 + n0 + (tx << 2)] = o;
    }
}

// ---------------- weight prep: fp32 (K,256) -> split bf16 [k/8][ldn][8] ----------------
struct PrepJob { const float* src; short* dhi; short* dlo; int ldn; int colofs; float sgn; };
struct PrepArgs { PrepJob j[28]; };

__global__ void prep_w(PrepArgs a) {
    const PrepJob jb = a.j[blockIdx.y];
    __shared__ float t[8][256];
    const int kg = blockIdx.x, tid = threadIdx.x;
    const int r = tid >> 5, c = (tid & 31) * 8;
    const float* src = jb.src + (size_t)(kg * 8 + r) * 256 + c;
    *(float4*)&t[r][c]     = *(const float4*)src;
    *(float4*)&t[r][c + 4] = *(const float4*)(src + 4);
    __syncthreads();
    const int n = tid;
    float x[8];
#pragma unroll
    for (int q = 0; q < 8; ++q) x[q] = t[q][n] * jb.sgn;
    uint4 h, l;
    h.x = cvt_pk_bf16(x[0], x[1]); h.y = cvt_pk_bf16(x[2], x[3]);
    h.z = cvt_pk_bf16(x[4], x[5]); h.w = cvt_pk_bf16(x[6], x[7]);
    l.x = cvt_pk_bf16(x[0] - bflo(h.x), x[1] - bfhi(h.x));
    l.y = cvt_pk_bf16(x[2] - bflo(h.y), x[3] - bfhi(h.y));
    l.z = cvt_pk_bf16(x[4] - bflo(h.z), x[5] - bfhi(h.z));
    l.w = cvt_pk_bf16(x[6] - bflo(h.w), x[7] - bfhi(h.w));
    const size_t o = ((size_t)kg * jb.ldn + jb.colofs + n) * 8;
    *(uint4*)&jb.dhi[o] = h;
    *(uint4*)&jb.dlo[o] = l;
}

// ---------------- LayerNorm: one wave per token, pre-split bf16 output ----------------
__global__ void ln_wave(const float* __restrict__ u, const float* __restrict__ sc,
                        const float* __restrict__ bs,
                        short* __restrict__ outH, short* __restrict__ outL) {
    const int lane = threadIdx.x & 63;
    const int w = threadIdx.x >> 6;
    const size_t tok = (size_t)blockIdx.x * 4 + w;
    const size_t base = tok * 256 + (size_t)lane * 4;
    const float4 x = *(const float4*)&u[base];
    float s = x.x + x.y + x.z + x.w;
#pragma unroll
    for (int off = 32; off; off >>= 1) s += __shfl_xor(s, off, 64);
    const float mean = s * (1.f / 256.f);
    const float dx = x.x - mean, dy = x.y - mean, dz = x.z - mean, dw = x.w - mean;
    float v = dx * dx + dy * dy + dz * dz + dw * dw;
#pragma unroll
    for (int off = 32; off; off >>= 1) v += __shfl_xor(v, off, 64);
    const float rstd = rsqrtf(v * (1.f / 256.f) + 1e-5f);
    const float4 s4 = *(const float4*)&sc[lane * 4];
    const float4 b4 = *(const float4*)&bs[lane * 4];
    float4 o;
    o.x = dx * rstd * s4.x + b4.x;
    o.y = dy * rstd * s4.y + b4.y;
    o.z = dz * rstd * s4.z + b4.z;
    o.w = dw * rstd * s4.w + b4.w;
    uint2 h, lo;
    split4(o, h, lo);
    *(uint2*)&outH[base] = h;
    *(uint2*)&outL[base] = lo;
}

// ---------------- Bu+ymr GEMM: A(v_r) reg-staged, W gl16, N up to 768 ----------------
__global__ __launch_bounds__(512, 4) void gemm_bu(
    const short* __restrict__ AH, const short* __restrict__ AL,
    const short* __restrict__ Whi_g, const short* __restrict__ Wlo_g,
    float* __restrict__ outBu, float* __restrict__ outY) {
    __shared__ short AsH[2][128 * 32], AsL[2][128 * 32];
    __shared__ short Wh[2][4 * 128 * 8], Wl[2][4 * 128 * 8];
    const int tid = threadIdx.x;
    const int m0 = blockIdx.x << 7, n0 = blockIdx.y << 7;
    const int wid = tid >> 6, l = tid & 63;
    const int wm = wid >> 2, wn = wid & 3;
    const int kq = l >> 4, lr = l & 15;
    const int sm = tid >> 2, sc = tid & 3;
    const int wslot = sc ^ ((sm >> 1) & 3);
    const int kgW = (tid >> 7) & 3, colw = tid & 127;

    f32x4 acc[4][2];
#pragma unroll
    for (int i = 0; i < 4; ++i)
#pragma unroll
        for (int j = 0; j < 2; ++j) acc[i][j] = {0.f, 0.f, 0.f, 0.f};

    auto stageW = [&](int k0, int buf) {
        const size_t so = ((size_t)((k0 >> 3) + kgW) * 768 + n0 + colw) * 8;
        gl16(Whi_g + so, &Wh[buf][(kgW * 128 + colw) * 8]);
        gl16(Wlo_g + so, &Wl[buf][(kgW * 128 + colw) * 8]);
    };
    auto loadA = [&](int k0, uint4& h, uint4& lo) {
        const size_t ab = (size_t)(m0 + sm) * 256 + k0 + sc * 8;
        h  = *(const uint4*)&AH[ab];
        lo = *(const uint4*)&AL[ab];
    };
    auto writeA = [&](int buf, const uint4 h, const uint4 lo) {
        const int cell = (sm * 4 + wslot) * 8;
        *(uint4*)&AsH[buf][cell] = h;
        *(uint4*)&AsL[buf][cell] = lo;
    };

    {
        uint4 p0, p1;
        loadA(0, p0, p1);
        stageW(0, 0);
        writeA(0, p0, p1);
    }
    const int sw = (lr >> 1) & 3;
    for (int t = 0; t < 8; ++t) {
        const int cur = t & 1, nxt = cur ^ 1;
        bar_top();                              // no vmcnt drain at barrier
        const bool pre = (t + 1 < 8);
        uint4 nh, nl;
        if (pre) {
            loadA((t + 1) * 32, nh, nl);        // A first (older than W)
            stageW((t + 1) * 32, nxt);
        }
        if (pre) wait_vm4(); else wait_vm0();   // drains only prev-phase W DMA
        short8 ah[4], am[4];
#pragma unroll
        for (int i = 0; i < 4; ++i) {
            const int r = wm * 64 + i * 16 + lr;
            const int cell = (r * 4 + (kq ^ sw)) * 8;
            ah[i] = *(const short8*)&AsH[cur][cell];
            am[i] = *(const short8*)&AsL[cur][cell];
        }
#pragma unroll
        for (int j = 0; j < 2; ++j) {
            const int col = wn * 32 + j * 16 + lr;
            const short8 wh = *(const short8*)&Wh[cur][(kq * 128 + col) * 8];
            const short8 wl = *(const short8*)&Wl[cur][(kq * 128 + col) * 8];
#pragma unroll
            for (int i = 0; i < 4; ++i) {
                acc[i][j] = __builtin_amdgcn_mfma_f32_16x16x32_bf16(ah[i], wh, acc[i][j], 0, 0, 0);
                acc[i][j] = __builtin_amdgcn_mfma_f32_16x16x32_bf16(ah[i], wl, acc[i][j], 0, 0, 0);
                acc[i][j] = __builtin_amdgcn_mfma_f32_16x16x32_bf16(am[i], wh, acc[i][j], 0, 0, 0);
            }
        }
        if (pre) writeA(nxt, nh, nl);
    }
    const bool isY = (blockIdx.y >= 4);
#pragma unroll
    for (int j = 0; j < 2; ++j) {
        const int col = n0 + wn * 32 + j * 16 + lr;
#pragma unroll
        for (int i = 0; i < 4; ++i) {
#pragma unroll
            for (int r = 0; r < 4; ++r) {
                const int row = m0 + wm * 64 + i * 16 + kq * 4 + r;
                const float o = acc[i][j][r];
                if (isY) outY[(size_t)row * 256 + (col - 512)] = o;
                else     outBu[(size_t)row * 512 + col] = o;
            }
        }
    }
}

// ---------------- C GEMM (K=512, A=Xl): g_l split; g_r PACKED into ymr slots ----------------
template <int WANT_R>
__global__ __launch_bounds__(512, 4) void gemm_c(
    const short* __restrict__ AH, const short* __restrict__ AL,
    const short* __restrict__ Whi_g, const short* __restrict__ Wlo_g,
    float* ymr,                       // in: fp32 ymr; out (WANT_R): packed bf16 g_r (NO restrict)
    short* __restrict__ glH, short* __restrict__ glL) {
    __shared__ short AsH[2][128 * 32], AsL[2][128 * 32];
    __shared__ short Wh[2][4 * 128 * 8], Wl[2][4 * 128 * 8];
    const int tid = threadIdx.x;
    const int m0 = blockIdx.x << 7, n0 = blockIdx.y << 7;
    const int wid = tid >> 6, l = tid & 63;
    const int wm = wid >> 2, wn = wid & 3;
    const int kq = l >> 4, lr = l & 15;
    const int sm = tid >> 2, sc = tid & 3;
    const int wslot = sc ^ ((sm >> 1) & 3);
    const int kgW = (tid >> 7) & 3, colw = tid & 127;

    f32x4 acc[4][2];
#pragma unroll
    for (int i = 0; i < 4; ++i)
#pragma unroll
        for (int j = 0; j < 2; ++j) acc[i][j] = {0.f, 0.f, 0.f, 0.f};

    auto stageW = [&](int k0, int buf) {
        const size_t so = ((size_t)((k0 >> 3) + kgW) * 256 + n0 + colw) * 8;
        gl16(Whi_g + so, &Wh[buf][(kgW * 128 + colw) * 8]);
        gl16(Wlo_g + so, &Wl[buf][(kgW * 128 + colw) * 8]);
    };
    auto loadA = [&](int k0, uint4& h, uint4& lo) {
        const size_t ab = (size_t)(m0 + sm) * 512 + k0 + sc * 8;
        h  = *(const uint4*)&AH[ab];
        lo = *(const uint4*)&AL[ab];
    };
    auto writeA = [&](int buf, const uint4 h, const uint4 lo) {
        const int cell = (sm * 4 + wslot) * 8;
        *(uint4*)&AsH[buf][cell] = h;
        *(uint4*)&AsL[buf][cell] = lo;
    };

    {
        uint4 p0, p1;
        loadA(0, p0, p1);
        stageW(0, 0);
        writeA(0, p0, p1);
    }
    const int sw = (lr >> 1) & 3;
    for (int t = 0; t < 16; ++t) {
        const int cur = t & 1, nxt = cur ^ 1;
        bar_top();
        const bool pre = (t + 1 < 16);
        uint4 nh, nl;
        if (pre) {
            loadA((t + 1) * 32, nh, nl);
            stageW((t + 1) * 32, nxt);
        }
        if (pre) wait_vm4(); else wait_vm0();
        short8 ah[4], am[4];
#pragma unroll
        for (int i = 0; i < 4; ++i) {
            const int r = wm * 64 + i * 16 + lr;
            const int cell = (r * 4 + (kq ^ sw)) * 8;
            ah[i] = *(const short8*)&AsH[cur][cell];
            am[i] = *(const short8*)&AsL[cur][cell];
        }
#pragma unroll
        for (int j = 0; j < 2; ++j) {
            const int col = wn * 32 + j * 16 + lr;
            const short8 wh = *(const short8*)&Wh[cur][(kq * 128 + col) * 8];
            const short8 wl = *(const short8*)&Wl[cur][(kq * 128 + col) * 8];
#pragma unroll
            for (int i = 0; i < 4; ++i) {
                acc[i][j] = __builtin_amdgcn_mfma_f32_16x16x32_bf16(ah[i], wh, acc[i][j], 0, 0, 0);
                acc[i][j] = __builtin_amdgcn_mfma_f32_16x16x32_bf16(ah[i], wl, acc[i][j], 0, 0, 0);
                acc[i][j] = __builtin_amdgcn_mfma_f32_16x16x32_bf16(am[i], wh, acc[i][j], 0, 0, 0);
            }
        }
        if (pre) writeA(nxt, nh, nl);
    }
#pragma unroll
    for (int j = 0; j < 2; ++j) {
        const int col = n0 + wn * 32 + j * 16 + lr;
#pragma unroll
        for (int i = 0; i < 4; ++i) {
#pragma unroll
            for (int r = 0; r < 4; ++r) {
                const int row = m0 + wm * 64 + i * 16 + kq * 4 + r;
                const size_t o = (size_t)row * 256 + col;
                const float y = acc[i][j][r];
                u16 h, lo;
                split1(gelu_tanh(y), h, lo);
                glH[o] = (short)h; glL[o] = (short)lo;
                if constexpr (WANT_R) {
                    const float yr = y + ymr[o];          // read fp32 ymr
                    split1(gelu_tanh(yr), h, lo);
                    ((u32*)ymr)[o] = (u32)h | ((u32)lo << 16);   // overwrite same slot: packed g_r
                }
            }
        }
    }
}

// ---------------- fused GLU GEMM, z-selected stream ----------------
// PK0: z==0 stream A is packed (h|l<<16 per elem); z==1 always split arrays.
template <int PK0>
__global__ __launch_bounds__(512, 4) void glu_dma(
    const u32* __restrict__ A0pk, const short* __restrict__ A0H, const short* __restrict__ A0L,
    float* __restrict__ u0,
    const short* __restrict__ A1H, const short* __restrict__ A1L, float* __restrict__ u1,
    const short* __restrict__ W1h, const short* __restrict__ W1l,
    const short* __restrict__ W2h, const short* __restrict__ W2l,
    const float* __restrict__ b1, const float* __restrict__ b2, int zero0) {
    __shared__ short AsH[2][128 * 32], AsL[2][128 * 32];
    __shared__ short Ws[2][4][4 * 64 * 8];
    const int z = blockIdx.z;
    const bool usePk = PK0 && (z == 0);
    const short* AH = z ? A1H : A0H;
    const short* AL = z ? A1L : A0L;
    float* u = z ? u1 : u0;
    const int tid = threadIdx.x;
    const int m0 = blockIdx.x << 7, n0 = blockIdx.y << 6;
    const int wid = tid >> 6, l = tid & 63;
    const int wm = wid >> 2, wn = wid & 3;
    const int kq = l >> 4, lr = l & 15;
    const int sm = tid >> 2, sc = tid & 3;
    const int wslot = sc ^ ((sm >> 1) & 3);
    const int kgW = (tid >> 6) & 3, colw = tid & 63, selLo = (tid >> 8) & 1;

    f32x4 acc1[4], acc2[4];
#pragma unroll
    for (int i = 0; i < 4; ++i) {
        acc1[i] = {0.f, 0.f, 0.f, 0.f};
        acc2[i] = {0.f, 0.f, 0.f, 0.f};
    }

    auto stageW = [&](int k0, int buf) {
        const size_t so = ((size_t)((k0 >> 3) + kgW) * 256 + n0 + colw) * 8;
        const short* s1 = selLo ? W1l : W1h;
        const short* s2 = selLo ? W2l : W2h;
        gl16(s1 + so, &Ws[buf][selLo][(kgW * 64 + colw) * 8]);
        gl16(s2 + so, &Ws[buf][2 + selLo][(kgW * 64 + colw) * 8]);
    };
    auto loadA = [&](int k0, uint4& h, uint4& lo) {
        const size_t ab = (size_t)(m0 + sm) * 256 + k0 + sc * 8;
        if (usePk) {
            const uint4 p0 = *(const uint4*)&A0pk[ab];
            const uint4 p1 = *(const uint4*)&A0pk[ab + 4];
            h.x = (p0.x & 0xFFFFu) | (p0.y << 16);
            lo.x = (p0.x >> 16)    | (p0.y & 0xFFFF0000u);
            h.y = (p0.z & 0xFFFFu) | (p0.w << 16);
            lo.y = (p0.z >> 16)    | (p0.w & 0xFFFF0000u);
            h.z = (p1.x & 0xFFFFu) | (p1.y << 16);
            lo.z = (p1.x >> 16)    | (p1.y & 0xFFFF0000u);
            h.w = (p1.z & 0xFFFFu) | (p1.w << 16);
            lo.w = (p1.z >> 16)    | (p1.w & 0xFFFF0000u);
        } else {
            h  = *(const uint4*)&AH[ab];
            lo = *(const uint4*)&AL[ab];
        }
    };
    auto writeA = [&](int buf, const uint4 h, const uint4 lo) {
        const int cell = (sm * 4 + wslot) * 8;
        *(uint4*)&AsH[buf][cell] = h;
        *(uint4*)&AsL[buf][cell] = lo;
    };

    {
        uint4 p0, p1;
        loadA(0, p0, p1);
        stageW(0, 0);
        writeA(0, p0, p1);
    }
    const int sw = (lr >> 1) & 3;
    for (int t = 0; t < 8; ++t) {
        const int cur = t & 1, nxt = cur ^ 1;
        bar_top();
        const bool pre = (t + 1 < 8);
        uint4 nh, nl;
        if (pre) {
            loadA((t + 1) * 32, nh, nl);
            stageW((t + 1) * 32, nxt);
        }
        if (pre) wait_vm4(); else wait_vm0();
        short8 ah[4], am[4];
#pragma unroll
        for (int i = 0; i < 4; ++i) {
            const int r = wm * 64 + i * 16 + lr;
            const int cell = (r * 4 + (kq ^ sw)) * 8;
            ah[i] = *(const short8*)&AsH[cur][cell];
            am[i] = *(const short8*)&AsL[cur][cell];
        }
        {
            const int col = wn * 16 + lr;
            const short8 w1h = *(const short8*)&Ws[cur][0][(kq * 64 + col) * 8];
            const short8 w1l = *(const short8*)&Ws[cur][1][(kq * 64 + col) * 8];
            const short8 w2h = *(const short8*)&Ws[cur][2][(kq * 64 + col) * 8];
            const short8 w2l = *(const short8*)&Ws[cur][3][(kq * 64 + col) * 8];
#pragma unroll
            for (int i = 0; i < 4; ++i) {
                acc1[i] = __builtin_amdgcn_mfma_f32_16x16x32_bf16(ah[i], w1h, acc1[i], 0, 0, 0);
                acc1[i] = __builtin_amdgcn_mfma_f32_16x16x32_bf16(ah[i], w1l, acc1[i], 0, 0, 0);
                acc1[i] = __builtin_amdgcn_mfma_f32_16x16x32_bf16(am[i], w1h, acc1[i], 0, 0, 0);
                acc2[i] = __builtin_amdgcn_mfma_f32_16x16x32_bf16(ah[i], w2h, acc2[i], 0, 0, 0);
                acc2[i] = __builtin_amdgcn_mfma_f32_16x16x32_bf16(ah[i], w2l, acc2[i], 0, 0, 0);
                acc2[i] = __builtin_amdgcn_mfma_f32_16x16x32_bf16(am[i], w2h, acc2[i], 0, 0, 0);
            }
        }
        if (pre) writeA(nxt, nh, nl);
    }
    {
        const int col = n0 + wn * 16 + lr;
        const float c1 = b1[col], c2 = b2[col];
#pragma unroll
        for (int i = 0; i < 4; ++i) {
#pragma unroll
            for (int r = 0; r < 4; ++r) {
                const int row = m0 + wm * 64 + i * 16 + kq * 4 + r;
                const size_t o = (size_t)row * 256 + col;
                if (zero0 && ((row & (NSEQ - 1)) == 0)) {
                    u[o] = 0.f;
                } else {
                    const float t1 = acc1[i][r] + c1;
                    const float t2 = acc2[i][r] + c2;
                    u[o] += t1 * (1.f / (1.f + __expf(-t2)));
                }
            }
        }
    }
}

// ---------------- embed GEMM: fp32 A (input), split in-kernel (runs once) ----------------
__global__ __launch_bounds__(512, 4) void gemm_embed(
    const float* __restrict__ A,
    const short* __restrict__ Whi_g, const short* __restrict__ Wlo_g,
    const float* __restrict__ bias,
    float* __restrict__ out0, float* __restrict__ out1) {
    __shared__ short As[2][2][4][128][8];
    __shared__ short Wsd[2][2][4][128][8];
    const int tid = threadIdx.x;
    const int m0 = blockIdx.x << 7, n0 = blockIdx.y << 7;
    const int wid = tid >> 6, l = tid & 63;
    const int wm = wid >> 2, wn = wid & 3;
    const int kq = l >> 4, lr = l & 15;
    const int sm = tid >> 2;
    const int klo = (tid & 3) * 4;
    const int kg0 = klo >> 3, sub0 = klo & 7;
    const int kgW = (tid >> 7) & 3, colw = tid & 127;

    f32x4 acc[4][2];
#pragma unroll
    for (int i = 0; i < 4; ++i)
#pragma unroll
        for (int j = 0; j < 2; ++j) acc[i][j] = {0.f, 0.f, 0.f, 0.f};

    auto stageW = [&](int k0, int buf) {
        const size_t so = ((size_t)((k0 >> 3) + kgW) * 256 + n0 + colw) * 8;
        gl16(Whi_g + so, &Wsd[buf][0][kgW][colw][0]);
        gl16(Wlo_g + so, &Wsd[buf][1][kgW][colw][0]);
    };
    auto loadA = [&](int k0, float4& v0, float4& v1) {
        const float* ap = A + (size_t)(m0 + sm) * 256 + k0 + klo;
        v0 = *(const float4*)ap;
        v1 = *(const float4*)(ap + 16);
    };
    auto writeA = [&](int buf, const float4 v0, const float4 v1) {
        uint2 h, lo;
        split4(v0, h, lo);
        *(uint2*)&As[buf][0][kg0][sm][sub0] = h;
        *(uint2*)&As[buf][1][kg0][sm][sub0] = lo;
        split4(v1, h, lo);
        *(uint2*)&As[buf][0][kg0 + 2][sm][sub0] = h;
        *(uint2*)&As[buf][1][kg0 + 2][sm][sub0] = lo;
    };

    {
        float4 p0, p1;
        loadA(0, p0, p1);
        stageW(0, 0);
        writeA(0, p0, p1);
    }
    for (int t = 0; t < 8; ++t) {
        const int cur = t & 1, nxt = cur ^ 1;
        bar_top();
        const bool pre = (t + 1 < 8);
        float4 nv0, nv1;
        if (pre) {
            loadA((t + 1) * 32, nv0, nv1);
            stageW((t + 1) * 32, nxt);
        }
        if (pre) wait_vm4(); else wait_vm0();
        short8 ah[4], am[4];
#pragma unroll
        for (int i = 0; i < 4; ++i) {
            const int row = wm * 64 + i * 16 + lr;
            ah[i] = *(const short8*)&As[cur][0][kq][row][0];
            am[i] = *(const short8*)&As[cur][1][kq][row][0];
        }
#pragma unroll
        for (int j = 0; j < 2; ++j) {
            const int col = wn * 32 + j * 16 + lr;
            const short8 wh = *(const short8*)&Wsd[cur][0][kq][col][0];
            const short8 wl = *(const short8*)&Wsd[cur][1][kq][col][0];
#pragma unroll
            for (int i = 0; i < 4; ++i) {
                acc[i][j] = __builtin_amdgcn_mfma_f32_16x16x32_bf16(ah[i], wh, acc[i][j], 0, 0, 0);
                acc[i][j] = __builtin_amdgcn_mfma_f32_16x16x32_bf16(ah[i], wl, acc[i][j], 0, 0, 0);
                acc[i][j] = __builtin_amdgcn_mfma_f32_16x16x32_bf16(am[i], wh, acc[i][j], 0, 0, 0);
            }
        }
        if (pre) writeA(nxt, nv0, nv1);
    }
#pragma unroll
    for (int j = 0; j < 2; ++j) {
        const int col = n0 + wn * 32 + j * 16 + lr;
        const float bv = bias[col];
#pragma unroll
        for (int i = 0; i < 4; ++i) {
#pragma unroll
            for (int r = 0; r < 4; ++r) {
                const int row = m0 + wm * 64 + i * 16 + kq * 4 + r;
                const float o = acc[i][j][r] + bv;
                out0[(size_t)row * 256 + col] = o;
                out1[(size_t)row * 256 + col] = o;
            }
        }
    }
}

// ---------------- chunked complex scan, 3 passes ----------------
__global__ void scan_p1(const float* __restrict__ Bu, const float* __restrict__ dt,
                        const float* __restrict__ Lre, const float* __restrict__ Lim,
                        const float* __restrict__ ldl,
                        float* __restrict__ Ard, float* __restrict__ Erd) {
    const int c = blockIdx.x % NCHUNK, b = blockIdx.x / NCHUNK;
    const int p = threadIdx.x;
    const float lam_r = -expf(Lre[p]);
    const float lam_i = Lim[p];
    const float del = expf(ldl[p]);
    float Ar = 1.f, Ai = 0.f, xr = 0.f, xi = 0.f;
    const int n0 = c * CHLEN;
    for (int n = n0; n < n0 + CHLEN; ++n) {
        const float e = dt[b * NSEQ + n] * del;
        const float amag = expf(lam_r * e);
        float sn, cs;
        sincosf(lam_i * e, &sn, &cs);
        const float are = amag * cs, aim = amag * sn;
        const size_t tok = ((size_t)b * NSEQ + n) * 512;
        const float br = Bu[tok + p], bi = Bu[tok + 256 + p];
        const float nxr = are * xr - aim * xi + br;
        const float nxi = are * xi + aim * xr + bi;
        xr = nxr; xi = nxi;
        const float nAr = are * Ar - aim * Ai;
        const float nAi = are * Ai + aim * Ar;
        Ar = nAr; Ai = nAi;
    }
    const size_t o = ((size_t)b * NCHUNK + c) * 512;
    Ard[o + p] = Ar; Ard[o + 256 + p] = Ai;
    Erd[o + p] = xr; Erd[o + 256 + p] = xi;
}

__global__ void scan_p2(const float* __restrict__ Ard, const float* __restrict__ Erd,
                        const float* __restrict__ ire, const float* __restrict__ iim,
                        float* __restrict__ S) {
    const int b = blockIdx.x, p = threadIdx.x;
    float sr = ire[p], si = iim[p];
    for (int c = 0; c < NCHUNK; ++c) {
        const size_t o = ((size_t)b * NCHUNK + c) * 512;
        S[o + p] = sr; S[o + 256 + p] = si;
        const float ar = Ard[o + p], ai = Ard[o + 256 + p];
        const float er = Erd[o + p], ei = Erd[o + 256 + p];
        const float nr = ar * sr - ai * si + er;
        const float ni = ar * si + ai * sr + ei;
        sr = nr; si = ni;
    }
}

// pass 3: replay; write X_left only, pre-split bf16 hi/lo
__global__ void scan_p3(const float* __restrict__ Bu, const float* __restrict__ dt,
                        const float* __restrict__ Lre, const float* __restrict__ Lim,
                        const float* __restrict__ ldl, const float* __restrict__ S,
                        short* __restrict__ XlH, short* __restrict__ XlL) {
    const int c = blockIdx.x % NCHUNK, b = blockIdx.x / NCHUNK;
    const int p = threadIdx.x;
    const float lam_r = -expf(Lre[p]);
    const float lam_i = Lim[p];
    const float del = expf(ldl[p]);
    const size_t o = ((size_t)b * NCHUNK + c) * 512;
    float xr = S[o + p], xi = S[o + 256 + p];
    const int n0 = c * CHLEN;
    for (int n = n0; n < n0 + CHLEN; ++n) {
        const float e = dt[b * NSEQ + n] * del;
        const float amag = expf(lam_r * e);
        float sn, cs;
        sincosf(lam_i * e, &sn, &cs);
        const float are = amag * cs, aim = amag * sn;
        const size_t tok = ((size_t)b * NSEQ + n) * 512;
        const float br = Bu[tok + p], bi = Bu[tok + 256 + p];
        const float lr = are * xr - aim * xi;
        const float li = are * xi + aim * xr;
        u16 h, lo;
        split1(lr, h, lo); XlH[tok + p] = (short)h;       XlL[tok + p] = (short)lo;
        split1(li, h, lo); XlH[tok + 256 + p] = (short)h; XlL[tok + 256 + p] = (short)lo;
        xr = lr + br;
        xi = li + bi;
    }
}

extern "C" void kernel_launch(void* const* d_in, const int* in_sizes, int n_in,
                              void* d_out, int out_size, void* d_ws, size_t ws_size,
                              hipStream_t stream) {
    const float* x_payload = (const float*)d_in[0];
    const float* dt        = (const float*)d_in[1];
    const float* embed_W   = (const float*)d_in[2];
    const float* embed_b   = (const float*)d_in[3];
    const float* ln_scale  = (const float*)d_in[4];
    const float* ln_bias   = (const float*)d_in[5];
    const float* Lambda_re = (const float*)d_in[6];
    const float* Lambda_im = (const float*)d_in[7];
    const float* log_delta = (const float*)d_in[8];
    const float* B_re      = (const float*)d_in[9];
    const float* B_im      = (const float*)d_in[10];
    const float* C_re      = (const float*)d_in[11];
    const float* C_im      = (const float*)d_in[12];
    const float* W1        = (const float*)d_in[13];
    const float* b1        = (const float*)d_in[14];
    const float* W2        = (const float*)d_in[15];
    const float* b2        = (const float*)d_in[16];
    const float* init_re   = (const float*)d_in[17];
    const float* init_im   = (const float*)d_in[18];

    const size_t WB_SZ = 32 * 768 * 8;          // shorts: [Bre|Bim|Mr]
    const size_t WC_SZ = 64 * 256 * 8;          // shorts: [Cre; -Cim] stacked K=512
    const size_t W_SZ  = 32 * 256 * 8;
    const size_t wbytes = (W_SZ + NLAYER * (WB_SZ + WC_SZ + 2 * W_SZ)) * 2 * 2
                        + (size_t)NLAYER * 65536 * 4 + 65536;

    // per-token: u_r 1024 + Bu 2048 + vbuf 1024 + Xl 2048 + ymr/gr 1024 = 7168 B
    auto footprint = [&](int g) -> size_t {
        size_t T = (size_t)g * NSEQ;
        return T * 7168 + (size_t)g * NCHUNK * 512 * 4 * 3 + wbytes + 65536;
    };
    int g = BATCH;
    while (g > 1 && footprint(g) > ws_size) g >>= 1;

    char* ws = (char*)d_ws;
    size_t off = 0;
    auto alloc = [&](size_t bytes) {
        void* p = ws + off;
        off = (off + bytes + 255) & ~(size_t)255;
        return p;
    };
    const size_t T = (size_t)g * NSEQ;
    const int Tg = (int)T;
    const int MT = Tg / 128;
    float* u_r   = (float*)alloc(T * 1024);
    float* BuB   = (float*)alloc(T * 2048);
    short* vbufH = (short*)alloc(T * 512);
    short* vbufL = (short*)alloc(T * 512);
    short* XlH   = (short*)alloc(T * 1024);
    short* XlL   = (short*)alloc(T * 1024);
    float* ymr   = (float*)alloc(T * 1024);     // fp32 ymr in; packed bf16 g_r out
    float* Ard   = (float*)alloc((size_t)g * NCHUNK * 512 * 4);
    float* Erd   = (float*)alloc((size_t)g * NCHUNK * 512 * 4);
    float* Sbuf  = (float*)alloc((size_t)g * NCHUNK * 512 * 4);
    short* embWh = (short*)alloc(W_SZ * 2);
    short* embWl = (short*)alloc(W_SZ * 2);
    short* WBh = (short*)alloc(NLAYER * WB_SZ * 2);
    short* WBl = (short*)alloc(NLAYER * WB_SZ * 2);
    short* WCh = (short*)alloc(NLAYER * WC_SZ * 2);
    short* WCl = (short*)alloc(NLAYER * WC_SZ * 2);
    short* W1h = (short*)alloc(NLAYER * W_SZ * 2);
    short* W1l = (short*)alloc(NLAYER * W_SZ * 2);
    short* W2h = (short*)alloc(NLAYER * W_SZ * 2);
    short* W2l = (short*)alloc(NLAYER * W_SZ * 2);
    float* MrF = (float*)alloc((size_t)NLAYER * 65536 * 4);
    short* glH = vbufH;   // vbuf dead after Bu GEMM; reuse for left gelu output
    short* glL = vbufL;

    // ---- one-shot weight prep: Mr GEMM, then split/transpose all weights ----
    mr_gemm<<<dim3(4, 4, 3), 256, 0, stream>>>(B_re, B_im, C_re, C_im, MrF);
    PrepArgs pa;
    int nj = 0;
    pa.j[nj++] = {embed_W, embWh, embWl, 256, 0, 1.f};
    for (int l = 0; l < NLAYER; ++l) {
        pa.j[nj++] = {B_re + (size_t)l * 65536, WBh + l * WB_SZ, WBl + l * WB_SZ, 768, 0, 1.f};
        pa.j[nj++] = {B_im + (size_t)l * 65536, WBh + l * WB_SZ, WBl + l * WB_SZ, 768, 256, 1.f};
        if (l < NLAYER - 1)
            pa.j[nj++] = {MrF + (size_t)l * 65536, WBh + l * WB_SZ, WBl + l * WB_SZ, 768, 512, 1.f};
        pa.j[nj++] = {C_re + (size_t)l * 65536, WCh + l * WC_SZ, WCl + l * WC_SZ, 256, 0, 1.f};
        pa.j[nj++] = {C_im + (size_t)l * 65536, WCh + l * WC_SZ + 32 * 256 * 8,
                      WCl + l * WC_SZ + 32 * 256 * 8, 256, 0, -1.f};
        pa.j[nj++] = {W1 + (size_t)l * 65536, W1h + l * W_SZ, W1l + l * W_SZ, 256, 0, 1.f};
        pa.j[nj++] = {W2 + (size_t)l * 65536, W2h + l * W_SZ, W2l + l * W_SZ, 256, 0, 1.f};
    }
    prep_w<<<dim3(32, nj), 256, 0, stream>>>(pa);

    for (int b0 = 0; b0 < BATCH; b0 += g) {
        const float* xg  = x_payload + (size_t)b0 * NSEQ * HDIM;
        const float* dtg = dt + (size_t)b0 * NSEQ;
        float* u_l = (float*)d_out + (size_t)b0 * NSEQ * HDIM;

        gemm_embed<<<dim3(MT, 2), 512, 0, stream>>>(xg, embWh, embWl, embed_b, u_r, u_l);

        for (int l = 0; l < NLAYER; ++l) {
            const bool wantR = (l < NLAYER - 1);
            const float* b1l = b1 + (size_t)l * 256;
            const float* b2l = b2 + (size_t)l * 256;
            const float* Lrl = Lambda_re + l * PDIM;
            const float* Lil = Lambda_im + l * PDIM;
            const float* ldll = log_delta + l * PDIM;
            const float* irl = init_re + l * PDIM;
            const float* iil = init_im + l * PDIM;
            const short* wbh = WBh + l * WB_SZ, *wbl = WBl + l * WB_SZ;
            const short* wch = WCh + l * WC_SZ, *wcl = WCl + l * WC_SZ;
            const short* w1hl = W1h + l * W_SZ, *w1ll = W1l + l * W_SZ;
            const short* w2hl = W2h + l * W_SZ, *w2ll = W2l + l * W_SZ;

            ln_wave<<<Tg / 4, 256, 0, stream>>>(u_r, ln_scale + l * HDIM, ln_bias + l * HDIM,
                                                vbufH, vbufL);
            gemm_bu<<<dim3(MT, wantR ? 6 : 4), 512, 0, stream>>>(
                vbufH, vbufL, wbh, wbl, BuB, ymr);
            scan_p1<<<g * NCHUNK, 256, 0, stream>>>(BuB, dtg, Lrl, Lil, ldll, Ard, Erd);
            scan_p2<<<g, 256, 0, stream>>>(Ard, Erd, irl, iil, Sbuf);
            scan_p3<<<g * NCHUNK, 256, 0, stream>>>(BuB, dtg, Lrl, Lil, ldll, Sbuf, XlH, XlL);
            if (wantR) {
                gemm_c<1><<<dim3(MT, 2), 512, 0, stream>>>(XlH, XlL, wch, wcl, ymr, glH, glL);
                glu_dma<1><<<dim3(MT, 4, 2), 512, 0, stream>>>(
                    (const u32*)ymr, nullptr, nullptr, u_r, glH, glL, u_l,
                    w1hl, w1ll, w2hl, w2ll, b1l, b2l, 0);
            } else {
                gemm_c<0><<<dim3(MT, 2), 512, 0, stream>>>(XlH, XlL, wch, wcl, ymr, glH, glL);
                glu_dma<0><<<dim3(MT, 4, 1), 512, 0, stream>>>(
                    nullptr, glH, glL, u_l, nullptr, nullptr, nullptr,
                    w1hl, w1ll, w2hl, w2ll, b1l, b2l, 1);
            }
        }
    }
}